// Round 3
// baseline (334.970 us; speedup 1.0000x reference)
//
#include <hip/hip_runtime.h>
#include <hip/hip_bf16.h>

typedef __attribute__((ext_vector_type(8))) short bf16x8;
typedef __attribute__((ext_vector_type(4))) float f32x4;

#define LDSG(g, l) __builtin_amdgcn_global_load_lds(                      \
    (const __attribute__((address_space(1))) void*)(g),                   \
    (__attribute__((address_space(3))) void*)(l), 16, 0, 0)

#define LOG2E 1.44269504088896f
#define RELSC 0.180336880111112f   /* 0.125 * log2(e) */

// ---------------- kernel 1: fp32 -> bf16 convert (hidden + Wq|Wk|Wv) --------
__global__ __launch_bounds__(256) void cvt_kernel(
    const float* __restrict__ hs,
    const float* __restrict__ wq, const float* __restrict__ wk,
    const float* __restrict__ wv,
    __hip_bfloat16* __restrict__ hbf, __hip_bfloat16* __restrict__ wbf)
{
  const int NH = (4 * 1024 * 1024) / 4;   // hidden quads
  const int NW = (1024 * 1024) / 4;       // per-W quads
  int i = blockIdx.x * 256 + threadIdx.x; // exact grid: NH + 3*NW quads
  float4 v;
  __hip_bfloat16* dst;
  if (i < NH) {
    v = ((const float4*)hs)[i];
    dst = hbf + (size_t)i * 4;
  } else {
    int j = i - NH;
    int which = j / NW, r = j - which * NW;
    const float* src = which == 0 ? wq : (which == 1 ? wk : wv);
    v = ((const float4*)src)[r];
    dst = wbf + (size_t)j * 4;
  }
  union { ushort4 u; __hip_bfloat16 b[4]; } o;
  o.b[0] = __float2bfloat16(v.x);
  o.b[1] = __float2bfloat16(v.y);
  o.b[2] = __float2bfloat16(v.z);
  o.b[3] = __float2bfloat16(v.w);
  *((ushort4*)dst) = o.u;
}

// ---------------- kernel 2: QKV GEMM  C[4096][3072] = A[4096][1024] @ W^T ---
// q scaled by 0.125*log2e and stored [b,h,s,d]; k stored [b,h,s,d];
// v stored TRANSPOSED [b,h,d,s] so attention reads V^T fragments directly.
__global__ __launch_bounds__(256) void qkv_gemm(
    const __hip_bfloat16* __restrict__ A,  // [4096][1024]
    const __hip_bfloat16* __restrict__ W,  // [3072][1024] (q,k,v stacked)
    const float* __restrict__ bq, const float* __restrict__ bk,
    const float* __restrict__ bv,
    __hip_bfloat16* __restrict__ qo, __hip_bfloat16* __restrict__ ko,
    __hip_bfloat16* __restrict__ vo)
{
  const int K = 1024;
  __shared__ __hip_bfloat16 As[128 * 64];
  __shared__ __hip_bfloat16 Bs[128 * 64];
  const int bid = blockIdx.x;
  const int bm = bid & 31, bn = bid >> 5;
  const int m0 = bm * 128, n0 = bn * 128;
  const int tid = threadIdx.x, wid = tid >> 6, lane = tid & 63;
  const int wm = wid >> 1, wn = wid & 1;

  f32x4 acc[4][4] = {};

  const int srow = lane >> 3;              // 0..7 (row within 8-row group)
  const int schunk = (lane & 7) ^ srow;    // swizzled 16B-chunk in row

  for (int k0 = 0; k0 < K; k0 += 64) {
#pragma unroll
    for (int p = 0; p < 4; ++p) {
      int r = (wid * 4 + p) * 8 + srow;    // 0..127
      LDSG(&A[(size_t)(m0 + r) * K + k0 + schunk * 8], &As[(wid * 4 + p) * 512]);
      LDSG(&W[(size_t)(n0 + r) * K + k0 + schunk * 8], &Bs[(wid * 4 + p) * 512]);
    }
    __syncthreads();
#pragma unroll
    for (int ks = 0; ks < 2; ++ks) {
      bf16x8 af[4], bfr[4];
#pragma unroll
      for (int mi = 0; mi < 4; ++mi) {
        int row = wm * 64 + mi * 16 + (lane & 15);
        int slot = (ks * 4 + (lane >> 4)) ^ (lane & 7);
        af[mi] = *(const bf16x8*)((const char*)As + row * 128 + slot * 16);
      }
#pragma unroll
      for (int ni = 0; ni < 4; ++ni) {
        int row = wn * 64 + ni * 16 + (lane & 15);
        int slot = (ks * 4 + (lane >> 4)) ^ (lane & 7);
        bfr[ni] = *(const bf16x8*)((const char*)Bs + row * 128 + slot * 16);
      }
#pragma unroll
      for (int mi = 0; mi < 4; ++mi)
#pragma unroll
        for (int ni = 0; ni < 4; ++ni)
          acc[mi][ni] = __builtin_amdgcn_mfma_f32_16x16x32_bf16(
              af[mi], bfr[ni], acc[mi][ni], 0, 0, 0);
    }
    __syncthreads();
  }

  // epilogue. C/D layout: col = lane&15, row = (lane>>4)*4+j.
#pragma unroll
  for (int ni = 0; ni < 4; ++ni) {
    int n = n0 + wn * 64 + ni * 16 + (lane & 15);
    int which = n >> 10;         // 0=q 1=k 2=v (uniform per block)
    int h = (n >> 6) & 15;
    int d = n & 63;
    const float* bias = which == 0 ? bq : (which == 1 ? bk : bv);
    float bval = bias[n & 1023];
    if (which == 2) {
      // v transposed: vo[(bh*64+d)*1024 + s], 4 consecutive s -> ushort4
#pragma unroll
      for (int mi = 0; mi < 4; ++mi) {
        int m = m0 + wm * 64 + mi * 16 + (lane >> 4) * 4;
        int b = m >> 10, s = m & 1023;
        union { ushort4 u; __hip_bfloat16 bb[4]; } o;
#pragma unroll
        for (int j = 0; j < 4; ++j)
          o.bb[j] = __float2bfloat16(acc[mi][ni][j] + bval);
        *(ushort4*)&vo[((size_t)((b * 16 + h) * 64 + d) << 10) + s] = o.u;
      }
    } else {
      __hip_bfloat16* dst = which == 0 ? qo : ko;
      float scale = (which == 0) ? RELSC : 1.0f; // q pre-scaled by inv_sqrt_d*log2e
#pragma unroll
      for (int mi = 0; mi < 4; ++mi) {
#pragma unroll
        for (int j = 0; j < 4; ++j) {
          int m = m0 + wm * 64 + mi * 16 + (lane >> 4) * 4 + j;
          int b = m >> 10, s = m & 1023;
          float val = (acc[mi][ni][j] + bval) * scale;
          dst[(((size_t)(b * 16 + h) << 10) + s) * 64 + d] = __float2bfloat16(val);
        }
      }
    }
  }
}

// ---------------- kernel 3: flash attention, barrier-free -------------------
// 1 wave per block; grid 4096 = 64 bh x 64 q-tiles of 16 rows. bh%8==bid%8
// pins all blocks of a (b,h) to one XCD so K/V (256KB) serve from its L2.
// K and V^T MFMA fragments are loaded DIRECTLY from global (no LDS staging,
// no __syncthreads anywhere). rel + K register-prefetched one iter ahead.
// Only LDS: wave-private 2KB P-transpose buffer (lgkmcnt-ordered, no barrier).
__global__ __launch_bounds__(64, 2) void attn_kernel(
    const __hip_bfloat16* __restrict__ qg, const __hip_bfloat16* __restrict__ kg,
    const __hip_bfloat16* __restrict__ vtg,
    const float* __restrict__ rel1, const float* __restrict__ rel2,
    const float* __restrict__ mask, float* __restrict__ out)
{
  __shared__ __hip_bfloat16 Ps[16 * 64];

  const int bid = blockIdx.x;
  const int bh = bid & 63, qt = bid >> 6;
  const int b = bh >> 4, h = bh & 15;
  const int lane = threadIdx.x;
  const int lg = lane >> 4, ln15 = lane & 15;

  const size_t kvbase = (size_t)bh << 16;
  const int q0 = qt * 16;

  // Q as B-operand fragment: col=ln15=q, contraction d = ks*32 + lg*8 + jj
  bf16x8 qf[2];
  qf[0] = *(const bf16x8*)&qg[kvbase + (size_t)(q0 + ln15) * 64 + lg * 8];
  qf[1] = *(const bf16x8*)&qg[kvbase + (size_t)(q0 + ln15) * 64 + 32 + lg * 8];

  f32x4 accO[4] = {};
  float mrun = -1e30f, lrun = 0.f;

  const float* relp1 = rel1 + ((size_t)bh << 20) + (size_t)(q0 + ln15) * 1024;
  const float* relp2 = rel2 + ((size_t)bh << 20) + (size_t)(q0 + ln15) * 1024;
  const float* maskp = mask + ((size_t)b << 10);

  // K fragment: A-operand row k = kb + ct*16 + ln15, contraction d
  // V^T fragment: A-operand row d = dt*16 + ln15, contraction k
#define LOAD_REL(R1, R2, KBO) do {                                          \
    _Pragma("unroll") for (int ct = 0; ct < 4; ++ct) {                      \
      R1[ct] = *(const float4*)&relp1[(KBO) + ct * 16 + lg * 4];            \
      R2[ct] = *(const float4*)&relp2[(KBO) + ct * 16 + lg * 4];            \
    } } while (0)

#define LOAD_K(KF, KBO) do {                                                \
    _Pragma("unroll") for (int ks = 0; ks < 2; ++ks)                        \
      _Pragma("unroll") for (int ct = 0; ct < 4; ++ct)                      \
        KF[ks * 4 + ct] = *(const bf16x8*)&kg[kvbase +                      \
            (size_t)((KBO) + ct * 16 + ln15) * 64 + ks * 32 + lg * 8];      \
    } while (0)

#define LOAD_V(VF, KBO) do {                                                \
    _Pragma("unroll") for (int ks = 0; ks < 2; ++ks)                        \
      _Pragma("unroll") for (int dt = 0; dt < 4; ++dt)                      \
        VF[ks * 4 + dt] = *(const bf16x8*)&vtg[kvbase +                     \
            (size_t)(dt * 16 + ln15) * 1024 + (KBO) + ks * 32 + lg * 8];    \
    } while (0)

#define BODY(RC1, RC2, KC, RN1, RN2, KN, KT) do {                           \
    bf16x8 vfr[8];                                                          \
    LOAD_V(vfr, (KT) * 64);                                                 \
    if ((KT) < 15) {                                                        \
      LOAD_REL(RN1, RN2, ((KT) + 1) * 64);                                  \
      LOAD_K(KN, ((KT) + 1) * 64);                                          \
    }                                                                       \
    f32x4 st[4] = {};                                                       \
    _Pragma("unroll") for (int ks = 0; ks < 2; ++ks)                        \
      _Pragma("unroll") for (int ct = 0; ct < 4; ++ct)                      \
        st[ct] = __builtin_amdgcn_mfma_f32_16x16x32_bf16(                   \
            KC[ks * 4 + ct], qf[ks], st[ct], 0, 0, 0);                      \
    float p[4][4]; float mt = -1e30f;                                       \
    _Pragma("unroll") for (int ct = 0; ct < 4; ++ct) {                      \
      float4 mv = *(const float4*)&maskp[(KT) * 64 + ct * 16 + lg * 4];     \
      _Pragma("unroll") for (int j = 0; j < 4; ++j) {                       \
        float sv = st[ct][j] +                                              \
                   RELSC * (((const float*)&RC1[ct])[j] +                   \
                            ((const float*)&RC2[ct])[j]) +                  \
                   LOG2E * ((const float*)&mv)[j];                          \
        p[ct][j] = sv; mt = fmaxf(mt, sv);                                  \
      }                                                                     \
    }                                                                       \
    mt = fmaxf(mt, __shfl_xor(mt, 16, 64));                                 \
    mt = fmaxf(mt, __shfl_xor(mt, 32, 64));                                 \
    float mnew = fmaxf(mrun, mt);                                           \
    float sc_ = __builtin_amdgcn_exp2f(mrun - mnew);                        \
    mrun = mnew;                                                            \
    float lsum = 0.f;                                                       \
    _Pragma("unroll") for (int ct = 0; ct < 4; ++ct)                        \
      _Pragma("unroll") for (int j = 0; j < 4; ++j) {                       \
        float e = __builtin_amdgcn_exp2f(p[ct][j] - mnew);                  \
        p[ct][j] = e; lsum += e;                                            \
      }                                                                     \
    lsum += __shfl_xor(lsum, 16, 64);                                       \
    lsum += __shfl_xor(lsum, 32, 64);                                       \
    lrun = lrun * sc_ + lsum;                                               \
    _Pragma("unroll") for (int dt = 0; dt < 4; ++dt) accO[dt] *= sc_;       \
    _Pragma("unroll") for (int ct = 0; ct < 4; ++ct) {                      \
      union { ushort4 u; __hip_bfloat16 bb[4]; } w;                         \
      _Pragma("unroll") for (int j = 0; j < 4; ++j)                         \
        w.bb[j] = __float2bfloat16(p[ct][j]);                               \
      *(ushort4*)((char*)Ps + ln15 * 128 +                                  \
                  ((ct * 32 + lg * 8) ^ ((ln15 & 7) << 4))) = w.u;          \
    }                                                                       \
    bf16x8 pt[2];                                                           \
    pt[0] = *(const bf16x8*)((const char*)Ps + ln15 * 128 +                 \
                             ((lg * 16) ^ ((ln15 & 7) << 4)));              \
    pt[1] = *(const bf16x8*)((const char*)Ps + ln15 * 128 +                 \
                             ((64 + lg * 16) ^ ((ln15 & 7) << 4)));         \
    _Pragma("unroll") for (int ks = 0; ks < 2; ++ks)                        \
      _Pragma("unroll") for (int dt = 0; dt < 4; ++dt)                      \
        accO[dt] = __builtin_amdgcn_mfma_f32_16x16x32_bf16(                 \
            vfr[ks * 4 + dt], pt[ks], accO[dt], 0, 0, 0);                   \
  } while (0)

  float4 r1a[4], r2a[4], r1b[4], r2b[4];
  bf16x8 kfa[8], kfb[8];

  LOAD_REL(r1a, r2a, 0);
  LOAD_K(kfa, 0);

#pragma unroll
  for (int t = 0; t < 8; ++t) {
    BODY(r1a, r2a, kfa, r1b, r2b, kfb, 2 * t);
    BODY(r1b, r2b, kfb, r1a, r2a, kfa, 2 * t + 1);
  }

  // epilogue: lane holds ctx^T[d=dt*16+lg*4+j][q=q0+ln15]; out fp32 [b,s,C]
  float rl = 1.0f / lrun;
#pragma unroll
  for (int dt = 0; dt < 4; ++dt) {
    float4 o;
    o.x = accO[dt][0] * rl;
    o.y = accO[dt][1] * rl;
    o.z = accO[dt][2] * rl;
    o.w = accO[dt][3] * rl;
    *(float4*)&out[((size_t)(b * 1024 + q0 + ln15)) * 1024 + h * 64 +
                   dt * 16 + lg * 4] = o;
  }
}

// ---------------------------------------------------------------------------
extern "C" void kernel_launch(void* const* d_in, const int* in_sizes, int n_in,
                              void* d_out, int out_size, void* d_ws,
                              size_t ws_size, hipStream_t stream) {
  const float* hs   = (const float*)d_in[0];
  const float* mask = (const float*)d_in[1];
  const float* rel1 = (const float*)d_in[2];
  const float* rel2 = (const float*)d_in[3];
  const float* Wq   = (const float*)d_in[4];
  const float* bq   = (const float*)d_in[5];
  const float* Wk   = (const float*)d_in[6];
  const float* bk   = (const float*)d_in[7];
  const float* Wv   = (const float*)d_in[8];
  const float* bv   = (const float*)d_in[9];

  char* ws = (char*)d_ws;
  __hip_bfloat16* hbf = (__hip_bfloat16*)(ws);              // 8 MB
  __hip_bfloat16* wbf = (__hip_bfloat16*)(ws + 8388608);    // 6 MB
  __hip_bfloat16* qb  = (__hip_bfloat16*)(ws + 14680064);   // 8 MB
  __hip_bfloat16* kb  = (__hip_bfloat16*)(ws + 23068672);   // 8 MB
  __hip_bfloat16* vtb = (__hip_bfloat16*)(ws + 31457280);   // 8 MB (total 38)

  cvt_kernel<<<7168, 256, 0, stream>>>(hs, Wq, Wk, Wv, hbf, wbf);
  qkv_gemm<<<768, 256, 0, stream>>>(hbf, wbf, bq, bk, bv, qb, kb, vtb);
  attn_kernel<<<4096, 64, 0, stream>>>(qb, kb, vtb, rel1, rel2, mask,
                                       (float*)d_out);
}

// Round 4
// 259.172 us; speedup vs baseline: 1.2925x; 1.2925x over previous
//
#include <hip/hip_runtime.h>
#include <hip/hip_bf16.h>

typedef __attribute__((ext_vector_type(8))) short bf16x8;
typedef __attribute__((ext_vector_type(4))) float f32x4;

#define LDSG(g, l) __builtin_amdgcn_global_load_lds(                      \
    (const __attribute__((address_space(1))) void*)(g),                   \
    (__attribute__((address_space(3))) void*)(l), 16, 0, 0)

#define LOG2E 1.44269504088896f
#define RELSC 0.180336880111112f   /* 0.125 * log2(e) */

// ---------------- kernel 1: fp32 -> bf16 convert (hidden + Wq|Wk|Wv) --------
__global__ __launch_bounds__(256) void cvt_kernel(
    const float* __restrict__ hs,
    const float* __restrict__ wq, const float* __restrict__ wk,
    const float* __restrict__ wv,
    __hip_bfloat16* __restrict__ hbf, __hip_bfloat16* __restrict__ wbf)
{
  const int NH = (4 * 1024 * 1024) / 4;   // hidden quads
  const int NW = (1024 * 1024) / 4;       // per-W quads
  int i = blockIdx.x * 256 + threadIdx.x; // exact grid: NH + 3*NW quads
  float4 v;
  __hip_bfloat16* dst;
  if (i < NH) {
    v = ((const float4*)hs)[i];
    dst = hbf + (size_t)i * 4;
  } else {
    int j = i - NH;
    int which = j / NW, r = j - which * NW;
    const float* src = which == 0 ? wq : (which == 1 ? wk : wv);
    v = ((const float4*)src)[r];
    dst = wbf + (size_t)j * 4;
  }
  union { ushort4 u; __hip_bfloat16 b[4]; } o;
  o.b[0] = __float2bfloat16(v.x);
  o.b[1] = __float2bfloat16(v.y);
  o.b[2] = __float2bfloat16(v.z);
  o.b[3] = __float2bfloat16(v.w);
  *((ushort4*)dst) = o.u;
}

// ---------------- kernel 2: QKV GEMM  C[4096][3072] = A[4096][1024] @ W^T ---
// q scaled by 0.125*log2e and stored [b,h,s,d]; k stored [b,h,s,d];
// v stored TRANSPOSED [b,h,d,s] so attention reads V^T fragments directly.
__global__ __launch_bounds__(256) void qkv_gemm(
    const __hip_bfloat16* __restrict__ A,  // [4096][1024]
    const __hip_bfloat16* __restrict__ W,  // [3072][1024] (q,k,v stacked)
    const float* __restrict__ bq, const float* __restrict__ bk,
    const float* __restrict__ bv,
    __hip_bfloat16* __restrict__ qo, __hip_bfloat16* __restrict__ ko,
    __hip_bfloat16* __restrict__ vo)
{
  const int K = 1024;
  __shared__ __hip_bfloat16 As[128 * 64];
  __shared__ __hip_bfloat16 Bs[128 * 64];
  const int bid = blockIdx.x;
  const int bm = bid & 31, bn = bid >> 5;
  const int m0 = bm * 128, n0 = bn * 128;
  const int tid = threadIdx.x, wid = tid >> 6, lane = tid & 63;
  const int wm = wid >> 1, wn = wid & 1;

  f32x4 acc[4][4] = {};

  const int srow = lane >> 3;              // 0..7 (row within 8-row group)
  const int schunk = (lane & 7) ^ srow;    // swizzled 16B-chunk in row

  for (int k0 = 0; k0 < K; k0 += 64) {
#pragma unroll
    for (int p = 0; p < 4; ++p) {
      int r = (wid * 4 + p) * 8 + srow;    // 0..127
      LDSG(&A[(size_t)(m0 + r) * K + k0 + schunk * 8], &As[(wid * 4 + p) * 512]);
      LDSG(&W[(size_t)(n0 + r) * K + k0 + schunk * 8], &Bs[(wid * 4 + p) * 512]);
    }
    __syncthreads();
#pragma unroll
    for (int ks = 0; ks < 2; ++ks) {
      bf16x8 af[4], bfr[4];
#pragma unroll
      for (int mi = 0; mi < 4; ++mi) {
        int row = wm * 64 + mi * 16 + (lane & 15);
        int slot = (ks * 4 + (lane >> 4)) ^ (lane & 7);
        af[mi] = *(const bf16x8*)((const char*)As + row * 128 + slot * 16);
      }
#pragma unroll
      for (int ni = 0; ni < 4; ++ni) {
        int row = wn * 64 + ni * 16 + (lane & 15);
        int slot = (ks * 4 + (lane >> 4)) ^ (lane & 7);
        bfr[ni] = *(const bf16x8*)((const char*)Bs + row * 128 + slot * 16);
      }
#pragma unroll
      for (int mi = 0; mi < 4; ++mi)
#pragma unroll
        for (int ni = 0; ni < 4; ++ni)
          acc[mi][ni] = __builtin_amdgcn_mfma_f32_16x16x32_bf16(
              af[mi], bfr[ni], acc[mi][ni], 0, 0, 0);
    }
    __syncthreads();
  }

  // epilogue. C/D layout: col = lane&15, row = (lane>>4)*4+j.
#pragma unroll
  for (int ni = 0; ni < 4; ++ni) {
    int n = n0 + wn * 64 + ni * 16 + (lane & 15);
    int which = n >> 10;         // 0=q 1=k 2=v (uniform per block)
    int h = (n >> 6) & 15;
    int d = n & 63;
    const float* bias = which == 0 ? bq : (which == 1 ? bk : bv);
    float bval = bias[n & 1023];
    if (which == 2) {
      // v transposed: vo[(bh*64+d)*1024 + s], 4 consecutive s -> ushort4
#pragma unroll
      for (int mi = 0; mi < 4; ++mi) {
        int m = m0 + wm * 64 + mi * 16 + (lane >> 4) * 4;
        int b = m >> 10, s = m & 1023;
        union { ushort4 u; __hip_bfloat16 bb[4]; } o;
#pragma unroll
        for (int j = 0; j < 4; ++j)
          o.bb[j] = __float2bfloat16(acc[mi][ni][j] + bval);
        *(ushort4*)&vo[((size_t)((b * 16 + h) * 64 + d) << 10) + s] = o.u;
      }
    } else {
      __hip_bfloat16* dst = which == 0 ? qo : ko;
      float scale = (which == 0) ? RELSC : 1.0f; // q pre-scaled by inv_sqrt_d*log2e
#pragma unroll
      for (int mi = 0; mi < 4; ++mi) {
#pragma unroll
        for (int j = 0; j < 4; ++j) {
          int m = m0 + wm * 64 + mi * 16 + (lane >> 4) * 4 + j;
          int b = m >> 10, s = m & 1023;
          float val = (acc[mi][ni][j] + bval) * scale;
          dst[(((size_t)(b * 16 + h) << 10) + s) * 64 + d] = __float2bfloat16(val);
        }
      }
    }
  }
}

// ---------------- kernel 3: flash attention, pipelined streaming ------------
// grid 1024 = 64 bh x 16 q-tiles of 64 rows; 4 independent waves per block,
// wave owns 16 q-rows. bh%8==bid%8 pins a (b,h)'s blocks to one XCD -> K/V
// (256KB/bh) L2-resident. K, V^T fragments read directly from global. rel + K
// register-prefetched one full body ahead; V issued at body top, consumed at
// body end. Mask lives in LDS (pre-scaled by log2e) so NO per-body load is
// consumed after the prefetches are issued -> counted vmcnt waits keep the
// pipeline full. Barrier only once (mask stage).
__global__ __launch_bounds__(256, 2) void attn_kernel(
    const __hip_bfloat16* __restrict__ qg, const __hip_bfloat16* __restrict__ kg,
    const __hip_bfloat16* __restrict__ vtg,
    const float* __restrict__ rel1, const float* __restrict__ rel2,
    const float* __restrict__ mask, float* __restrict__ out)
{
  __shared__ float Ml[1024];
  __shared__ __hip_bfloat16 Ps[4][16 * 64];

  const int bid = blockIdx.x;
  const int bh = bid & 63, qt = bid >> 6;
  const int b = bh >> 4, h = bh & 15;
  const int tid = threadIdx.x, wid = tid >> 6, lane = tid & 63;
  const int lg = lane >> 4, ln15 = lane & 15;

  const size_t kvbase = (size_t)bh << 16;
  const int q0 = qt * 64 + wid * 16;

  // stage mask (pre-scaled by log2e) into LDS once
  {
    float4 mv = *(const float4*)&mask[((size_t)b << 10) + tid * 4];
    float4 sm;
    sm.x = mv.x * LOG2E; sm.y = mv.y * LOG2E;
    sm.z = mv.z * LOG2E; sm.w = mv.w * LOG2E;
    *(float4*)&Ml[tid * 4] = sm;
  }
  __syncthreads();

  // Q as B-operand fragment: col=ln15=q, contraction d = ks*32 + lg*8 + jj
  bf16x8 qf[2];
  qf[0] = *(const bf16x8*)&qg[kvbase + (size_t)(q0 + ln15) * 64 + lg * 8];
  qf[1] = *(const bf16x8*)&qg[kvbase + (size_t)(q0 + ln15) * 64 + 32 + lg * 8];

  f32x4 accO[4] = {};
  float mrun = -1e30f, lrun = 0.f;

  const float* relp1 = rel1 + ((size_t)bh << 20) + (size_t)(q0 + ln15) * 1024;
  const float* relp2 = rel2 + ((size_t)bh << 20) + (size_t)(q0 + ln15) * 1024;

#define LOAD_REL(R1, R2, KBO) do {                                          \
    _Pragma("unroll") for (int ct = 0; ct < 4; ++ct) {                      \
      R1[ct] = *(const float4*)&relp1[(KBO) + ct * 16 + lg * 4];            \
      R2[ct] = *(const float4*)&relp2[(KBO) + ct * 16 + lg * 4];            \
    } } while (0)

#define LOAD_K(KF, KBO) do {                                                \
    _Pragma("unroll") for (int ks = 0; ks < 2; ++ks)                        \
      _Pragma("unroll") for (int ct = 0; ct < 4; ++ct)                      \
        KF[ks * 4 + ct] = *(const bf16x8*)&kg[kvbase +                      \
            (size_t)((KBO) + ct * 16 + ln15) * 64 + ks * 32 + lg * 8];      \
    } while (0)

#define LOAD_V(VF, KBO) do {                                                \
    _Pragma("unroll") for (int ks = 0; ks < 2; ++ks)                        \
      _Pragma("unroll") for (int dt = 0; dt < 4; ++dt)                      \
        VF[ks * 4 + dt] = *(const bf16x8*)&vtg[kvbase +                     \
            (size_t)(dt * 16 + ln15) * 1024 + (KBO) + ks * 32 + lg * 8];    \
    } while (0)

// COMPUTE consumes (RC1,RC2,KC) loaded one body earlier and vfr loaded at
// this body's top; it issues nothing -> waits are counted, prefetch survives.
#define COMPUTE(RC1, RC2, KC, KT) do {                                      \
    f32x4 st[4] = {};                                                       \
    _Pragma("unroll") for (int ks = 0; ks < 2; ++ks)                        \
      _Pragma("unroll") for (int ct = 0; ct < 4; ++ct)                      \
        st[ct] = __builtin_amdgcn_mfma_f32_16x16x32_bf16(                   \
            KC[ks * 4 + ct], qf[ks], st[ct], 0, 0, 0);                      \
    float p[4][4]; float mt = -1e30f;                                       \
    _Pragma("unroll") for (int ct = 0; ct < 4; ++ct) {                      \
      float4 mv = *(const float4*)&Ml[(KT) * 64 + ct * 16 + lg * 4];        \
      _Pragma("unroll") for (int j = 0; j < 4; ++j) {                       \
        float sv = st[ct][j] +                                              \
                   RELSC * (((const float*)&RC1[ct])[j] +                   \
                            ((const float*)&RC2[ct])[j]) +                  \
                   ((const float*)&mv)[j];                                  \
        p[ct][j] = sv; mt = fmaxf(mt, sv);                                  \
      }                                                                     \
    }                                                                       \
    mt = fmaxf(mt, __shfl_xor(mt, 16, 64));                                 \
    mt = fmaxf(mt, __shfl_xor(mt, 32, 64));                                 \
    float mnew = fmaxf(mrun, mt);                                           \
    float sc_ = __builtin_amdgcn_exp2f(mrun - mnew);                        \
    mrun = mnew;                                                            \
    float lsum = 0.f;                                                       \
    _Pragma("unroll") for (int ct = 0; ct < 4; ++ct)                        \
      _Pragma("unroll") for (int j = 0; j < 4; ++j) {                       \
        float e = __builtin_amdgcn_exp2f(p[ct][j] - mnew);                  \
        p[ct][j] = e; lsum += e;                                            \
      }                                                                     \
    lsum += __shfl_xor(lsum, 16, 64);                                       \
    lsum += __shfl_xor(lsum, 32, 64);                                       \
    lrun = lrun * sc_ + lsum;                                               \
    _Pragma("unroll") for (int dt = 0; dt < 4; ++dt) accO[dt] *= sc_;       \
    __hip_bfloat16* Pw = &Ps[wid][0];                                       \
    _Pragma("unroll") for (int ct = 0; ct < 4; ++ct) {                      \
      union { ushort4 u; __hip_bfloat16 bb[4]; } w;                         \
      _Pragma("unroll") for (int j = 0; j < 4; ++j)                         \
        w.bb[j] = __float2bfloat16(p[ct][j]);                               \
      *(ushort4*)((char*)Pw + ln15 * 128 +                                  \
                  ((ct * 32 + lg * 8) ^ ((ln15 & 7) << 4))) = w.u;          \
    }                                                                       \
    bf16x8 pt[2];                                                           \
    pt[0] = *(const bf16x8*)((const char*)Pw + ln15 * 128 +                 \
                             ((lg * 16) ^ ((ln15 & 7) << 4)));              \
    pt[1] = *(const bf16x8*)((const char*)Pw + ln15 * 128 +                 \
                             ((64 + lg * 16) ^ ((ln15 & 7) << 4)));         \
    _Pragma("unroll") for (int ks = 0; ks < 2; ++ks)                        \
      _Pragma("unroll") for (int dt = 0; dt < 4; ++dt)                      \
        accO[dt] = __builtin_amdgcn_mfma_f32_16x16x32_bf16(                 \
            vfr[ks * 4 + dt], pt[ks], accO[dt], 0, 0, 0);                   \
  } while (0)

#define BODY_PF(RC1, RC2, KC, RN1, RN2, KN, KT) do {                        \
    bf16x8 vfr[8];                                                          \
    LOAD_V(vfr, (KT) * 64);                                                 \
    LOAD_REL(RN1, RN2, ((KT) + 1) * 64);                                    \
    LOAD_K(KN, ((KT) + 1) * 64);                                            \
    COMPUTE(RC1, RC2, KC, KT);                                              \
  } while (0)

#define BODY_NP(RC1, RC2, KC, KT) do {                                      \
    bf16x8 vfr[8];                                                          \
    LOAD_V(vfr, (KT) * 64);                                                 \
    COMPUTE(RC1, RC2, KC, KT);                                              \
  } while (0)

  float4 r1a[4], r2a[4], r1b[4], r2b[4];
  bf16x8 kfa[8], kfb[8];

  LOAD_REL(r1a, r2a, 0);
  LOAD_K(kfa, 0);

  for (int t = 0; t < 7; ++t) {
    BODY_PF(r1a, r2a, kfa, r1b, r2b, kfb, 2 * t);
    BODY_PF(r1b, r2b, kfb, r1a, r2a, kfa, 2 * t + 1);
  }
  BODY_PF(r1a, r2a, kfa, r1b, r2b, kfb, 14);
  BODY_NP(r1b, r2b, kfb, 15);

  // epilogue: lane holds ctx^T[d=dt*16+lg*4+j][q=q0+ln15]; out fp32 [b,s,C]
  float rl = 1.0f / lrun;
#pragma unroll
  for (int dt = 0; dt < 4; ++dt) {
    float4 o;
    o.x = accO[dt][0] * rl;
    o.y = accO[dt][1] * rl;
    o.z = accO[dt][2] * rl;
    o.w = accO[dt][3] * rl;
    *(float4*)&out[((size_t)(b * 1024 + q0 + ln15)) * 1024 + h * 64 +
                   dt * 16 + lg * 4] = o;
  }
}

// ---------------------------------------------------------------------------
extern "C" void kernel_launch(void* const* d_in, const int* in_sizes, int n_in,
                              void* d_out, int out_size, void* d_ws,
                              size_t ws_size, hipStream_t stream) {
  const float* hs   = (const float*)d_in[0];
  const float* mask = (const float*)d_in[1];
  const float* rel1 = (const float*)d_in[2];
  const float* rel2 = (const float*)d_in[3];
  const float* Wq   = (const float*)d_in[4];
  const float* bq   = (const float*)d_in[5];
  const float* Wk   = (const float*)d_in[6];
  const float* bk   = (const float*)d_in[7];
  const float* Wv   = (const float*)d_in[8];
  const float* bv   = (const float*)d_in[9];

  char* ws = (char*)d_ws;
  __hip_bfloat16* hbf = (__hip_bfloat16*)(ws);              // 8 MB
  __hip_bfloat16* wbf = (__hip_bfloat16*)(ws + 8388608);    // 6 MB
  __hip_bfloat16* qb  = (__hip_bfloat16*)(ws + 14680064);   // 8 MB
  __hip_bfloat16* kb  = (__hip_bfloat16*)(ws + 23068672);   // 8 MB
  __hip_bfloat16* vtb = (__hip_bfloat16*)(ws + 31457280);   // 8 MB (total 38)

  cvt_kernel<<<7168, 256, 0, stream>>>(hs, Wq, Wk, Wv, hbf, wbf);
  qkv_gemm<<<768, 256, 0, stream>>>(hbf, wbf, bq, bk, bv, qb, kb, vtb);
  attn_kernel<<<1024, 256, 0, stream>>>(qb, kb, vtb, rel1, rel2, mask,
                                        (float*)d_out);
}

// Round 5
// 244.264 us; speedup vs baseline: 1.3713x; 1.0610x over previous
//
#include <hip/hip_runtime.h>
#include <hip/hip_bf16.h>

typedef __attribute__((ext_vector_type(8))) short bf16x8;
typedef __attribute__((ext_vector_type(4))) float f32x4;

#define LDSG(g, l) __builtin_amdgcn_global_load_lds(                      \
    (const __attribute__((address_space(1))) void*)(g),                   \
    (__attribute__((address_space(3))) void*)(l), 16, 0, 0)

#define LOG2E 1.44269504088896f
#define RELSC 0.180336880111112f   /* 0.125 * log2(e) */

// ---------------- kernel 1: fp32 -> bf16 convert (hidden + Wq|Wk|Wv) --------
__global__ __launch_bounds__(256) void cvt_kernel(
    const float* __restrict__ hs,
    const float* __restrict__ wq, const float* __restrict__ wk,
    const float* __restrict__ wv,
    __hip_bfloat16* __restrict__ hbf, __hip_bfloat16* __restrict__ wbf)
{
  const int NH = (4 * 1024 * 1024) / 4;   // hidden quads
  const int NW = (1024 * 1024) / 4;       // per-W quads
  int i = blockIdx.x * 256 + threadIdx.x; // exact grid: NH + 3*NW quads
  float4 v;
  __hip_bfloat16* dst;
  if (i < NH) {
    v = ((const float4*)hs)[i];
    dst = hbf + (size_t)i * 4;
  } else {
    int j = i - NH;
    int which = j / NW, r = j - which * NW;
    const float* src = which == 0 ? wq : (which == 1 ? wk : wv);
    v = ((const float4*)src)[r];
    dst = wbf + (size_t)j * 4;
  }
  union { ushort4 u; __hip_bfloat16 b[4]; } o;
  o.b[0] = __float2bfloat16(v.x);
  o.b[1] = __float2bfloat16(v.y);
  o.b[2] = __float2bfloat16(v.z);
  o.b[3] = __float2bfloat16(v.w);
  *((ushort4*)dst) = o.u;
}

// ---------------- kernel 2: QKV GEMM  C[4096][3072] = A[4096][1024] @ W^T ---
// q scaled by 0.125*log2e and stored [b,h,s,d]; k stored [b,h,s,d];
// v stored TRANSPOSED [b,h,d,s] so attention reads V^T fragments directly.
__global__ __launch_bounds__(256) void qkv_gemm(
    const __hip_bfloat16* __restrict__ A,  // [4096][1024]
    const __hip_bfloat16* __restrict__ W,  // [3072][1024] (q,k,v stacked)
    const float* __restrict__ bq, const float* __restrict__ bk,
    const float* __restrict__ bv,
    __hip_bfloat16* __restrict__ qo, __hip_bfloat16* __restrict__ ko,
    __hip_bfloat16* __restrict__ vo)
{
  const int K = 1024;
  __shared__ __hip_bfloat16 As[128 * 64];
  __shared__ __hip_bfloat16 Bs[128 * 64];
  const int bid = blockIdx.x;
  const int bm = bid & 31, bn = bid >> 5;
  const int m0 = bm * 128, n0 = bn * 128;
  const int tid = threadIdx.x, wid = tid >> 6, lane = tid & 63;
  const int wm = wid >> 1, wn = wid & 1;

  f32x4 acc[4][4] = {};

  const int srow = lane >> 3;              // 0..7 (row within 8-row group)
  const int schunk = (lane & 7) ^ srow;    // swizzled 16B-chunk in row

  for (int k0 = 0; k0 < K; k0 += 64) {
#pragma unroll
    for (int p = 0; p < 4; ++p) {
      int r = (wid * 4 + p) * 8 + srow;    // 0..127
      LDSG(&A[(size_t)(m0 + r) * K + k0 + schunk * 8], &As[(wid * 4 + p) * 512]);
      LDSG(&W[(size_t)(n0 + r) * K + k0 + schunk * 8], &Bs[(wid * 4 + p) * 512]);
    }
    __syncthreads();
#pragma unroll
    for (int ks = 0; ks < 2; ++ks) {
      bf16x8 af[4], bfr[4];
#pragma unroll
      for (int mi = 0; mi < 4; ++mi) {
        int row = wm * 64 + mi * 16 + (lane & 15);
        int slot = (ks * 4 + (lane >> 4)) ^ (lane & 7);
        af[mi] = *(const bf16x8*)((const char*)As + row * 128 + slot * 16);
      }
#pragma unroll
      for (int ni = 0; ni < 4; ++ni) {
        int row = wn * 64 + ni * 16 + (lane & 15);
        int slot = (ks * 4 + (lane >> 4)) ^ (lane & 7);
        bfr[ni] = *(const bf16x8*)((const char*)Bs + row * 128 + slot * 16);
      }
#pragma unroll
      for (int mi = 0; mi < 4; ++mi)
#pragma unroll
        for (int ni = 0; ni < 4; ++ni)
          acc[mi][ni] = __builtin_amdgcn_mfma_f32_16x16x32_bf16(
              af[mi], bfr[ni], acc[mi][ni], 0, 0, 0);
    }
    __syncthreads();
  }

  // epilogue. C/D layout: col = lane&15, row = (lane>>4)*4+j.
#pragma unroll
  for (int ni = 0; ni < 4; ++ni) {
    int n = n0 + wn * 64 + ni * 16 + (lane & 15);
    int which = n >> 10;         // 0=q 1=k 2=v (uniform per block)
    int h = (n >> 6) & 15;
    int d = n & 63;
    const float* bias = which == 0 ? bq : (which == 1 ? bk : bv);
    float bval = bias[n & 1023];
    if (which == 2) {
      // v transposed: vo[(bh*64+d)*1024 + s], 4 consecutive s -> ushort4
#pragma unroll
      for (int mi = 0; mi < 4; ++mi) {
        int m = m0 + wm * 64 + mi * 16 + (lane >> 4) * 4;
        int b = m >> 10, s = m & 1023;
        union { ushort4 u; __hip_bfloat16 bb[4]; } o;
#pragma unroll
        for (int j = 0; j < 4; ++j)
          o.bb[j] = __float2bfloat16(acc[mi][ni][j] + bval);
        *(ushort4*)&vo[((size_t)((b * 16 + h) * 64 + d) << 10) + s] = o.u;
      }
    } else {
      __hip_bfloat16* dst = which == 0 ? qo : ko;
      float scale = (which == 0) ? RELSC : 1.0f; // q pre-scaled by inv_sqrt_d*log2e
#pragma unroll
      for (int mi = 0; mi < 4; ++mi) {
#pragma unroll
        for (int j = 0; j < 4; ++j) {
          int m = m0 + wm * 64 + mi * 16 + (lane >> 4) * 4 + j;
          int b = m >> 10, s = m & 1023;
          float val = (acc[mi][ni][j] + bval) * scale;
          dst[(((size_t)(b * 16 + h) << 10) + s) * 64 + d] = __float2bfloat16(val);
        }
      }
    }
  }
}

// ---------------- kernel 3: flash attention, sched_barrier-pinned pipeline --
// grid 1024 = 64 bh x 16 q-tiles of 64 rows; 4 independent waves per block.
// bh%8==bid%8 pins a (b,h)'s blocks to one XCD -> K/V (256KB/bh, 2MB/XCD)
// L2-resident. Per body, program order pinned by sched_barrier(0):
//   LOAD_K(cur) LOAD_V(cur) | SB | LOAD_REL(next) | SB | COMPUTE
// FIFO vmcnt: QK^T waits K_cur -> vmcnt(24); PV waits V_cur -> vmcnt(16);
// rel_cur retired one body ago. The rel HBM stream is always one body
// (~3 us >> 900 cy) in flight. Mask in LDS (pre-scaled by log2e) so no
// global load is consumed after the prefetch issues.
__global__ __launch_bounds__(256, 2) void attn_kernel(
    const __hip_bfloat16* __restrict__ qg, const __hip_bfloat16* __restrict__ kg,
    const __hip_bfloat16* __restrict__ vtg,
    const float* __restrict__ rel1, const float* __restrict__ rel2,
    const float* __restrict__ mask, float* __restrict__ out)
{
  __shared__ float Ml[1024];
  __shared__ __hip_bfloat16 Ps[4][16 * 64];

  const int bid = blockIdx.x;
  const int bh = bid & 63, qt = bid >> 6;
  const int b = bh >> 4, h = bh & 15;
  const int tid = threadIdx.x, wid = tid >> 6, lane = tid & 63;
  const int lg = lane >> 4, ln15 = lane & 15;

  const size_t kvbase = (size_t)bh << 16;
  const int q0 = qt * 64 + wid * 16;

  // stage mask (pre-scaled by log2e) into LDS once
  {
    float4 mv = *(const float4*)&mask[((size_t)b << 10) + tid * 4];
    float4 sm;
    sm.x = mv.x * LOG2E; sm.y = mv.y * LOG2E;
    sm.z = mv.z * LOG2E; sm.w = mv.w * LOG2E;
    *(float4*)&Ml[tid * 4] = sm;
  }
  __syncthreads();

  // Q as B-operand fragment: col=ln15=q, contraction d = ks*32 + lg*8 + jj
  bf16x8 qf[2];
  qf[0] = *(const bf16x8*)&qg[kvbase + (size_t)(q0 + ln15) * 64 + lg * 8];
  qf[1] = *(const bf16x8*)&qg[kvbase + (size_t)(q0 + ln15) * 64 + 32 + lg * 8];

  f32x4 accO[4] = {};
  float mrun = -1e30f, lrun = 0.f;

  const float* relp1 = rel1 + ((size_t)bh << 20) + (size_t)(q0 + ln15) * 1024;
  const float* relp2 = rel2 + ((size_t)bh << 20) + (size_t)(q0 + ln15) * 1024;

#define LOAD_REL(R1, R2, KBO) do {                                          \
    _Pragma("unroll") for (int ct = 0; ct < 4; ++ct) {                      \
      R1[ct] = *(const float4*)&relp1[(KBO) + ct * 16 + lg * 4];            \
      R2[ct] = *(const float4*)&relp2[(KBO) + ct * 16 + lg * 4];            \
    } } while (0)

#define LOAD_K(KF, KBO) do {                                                \
    _Pragma("unroll") for (int ks = 0; ks < 2; ++ks)                        \
      _Pragma("unroll") for (int ct = 0; ct < 4; ++ct)                      \
        KF[ks * 4 + ct] = *(const bf16x8*)&kg[kvbase +                      \
            (size_t)((KBO) + ct * 16 + ln15) * 64 + ks * 32 + lg * 8];      \
    } while (0)

#define LOAD_V(VF, KBO) do {                                                \
    _Pragma("unroll") for (int ks = 0; ks < 2; ++ks)                        \
      _Pragma("unroll") for (int dt = 0; dt < 4; ++dt)                      \
        VF[ks * 4 + dt] = *(const bf16x8*)&vtg[kvbase +                     \
            (size_t)(dt * 16 + ln15) * 1024 + (KBO) + ks * 32 + lg * 8];    \
    } while (0)

// COMPUTE consumes rel (loaded one body earlier), kfr/vfr (this body's top).
#define COMPUTE(RC1, RC2, KT) do {                                          \
    f32x4 st[4] = {};                                                       \
    _Pragma("unroll") for (int ks = 0; ks < 2; ++ks)                        \
      _Pragma("unroll") for (int ct = 0; ct < 4; ++ct)                      \
        st[ct] = __builtin_amdgcn_mfma_f32_16x16x32_bf16(                   \
            kfr[ks * 4 + ct], qf[ks], st[ct], 0, 0, 0);                     \
    float p[4][4]; float mt = -1e30f;                                       \
    _Pragma("unroll") for (int ct = 0; ct < 4; ++ct) {                      \
      float4 mv = *(const float4*)&Ml[(KT) * 64 + ct * 16 + lg * 4];        \
      _Pragma("unroll") for (int j = 0; j < 4; ++j) {                       \
        float sv = st[ct][j] +                                              \
                   RELSC * (((const float*)&RC1[ct])[j] +                   \
                            ((const float*)&RC2[ct])[j]) +                  \
                   ((const float*)&mv)[j];                                  \
        p[ct][j] = sv; mt = fmaxf(mt, sv);                                  \
      }                                                                     \
    }                                                                       \
    mt = fmaxf(mt, __shfl_xor(mt, 16, 64));                                 \
    mt = fmaxf(mt, __shfl_xor(mt, 32, 64));                                 \
    float mnew = fmaxf(mrun, mt);                                           \
    float sc_ = __builtin_amdgcn_exp2f(mrun - mnew);                        \
    mrun = mnew;                                                            \
    float lsum = 0.f;                                                       \
    _Pragma("unroll") for (int ct = 0; ct < 4; ++ct)                        \
      _Pragma("unroll") for (int j = 0; j < 4; ++j) {                       \
        float e = __builtin_amdgcn_exp2f(p[ct][j] - mnew);                  \
        p[ct][j] = e; lsum += e;                                            \
      }                                                                     \
    lsum += __shfl_xor(lsum, 16, 64);                                       \
    lsum += __shfl_xor(lsum, 32, 64);                                       \
    lrun = lrun * sc_ + lsum;                                               \
    _Pragma("unroll") for (int dt = 0; dt < 4; ++dt) accO[dt] *= sc_;       \
    __hip_bfloat16* Pw = &Ps[wid][0];                                       \
    _Pragma("unroll") for (int ct = 0; ct < 4; ++ct) {                      \
      union { ushort4 u; __hip_bfloat16 bb[4]; } w;                         \
      _Pragma("unroll") for (int j = 0; j < 4; ++j)                         \
        w.bb[j] = __float2bfloat16(p[ct][j]);                               \
      *(ushort4*)((char*)Pw + ln15 * 128 +                                  \
                  ((ct * 32 + lg * 8) ^ ((ln15 & 7) << 4))) = w.u;          \
    }                                                                       \
    bf16x8 pt[2];                                                           \
    pt[0] = *(const bf16x8*)((const char*)Pw + ln15 * 128 +                 \
                             ((lg * 16) ^ ((ln15 & 7) << 4)));              \
    pt[1] = *(const bf16x8*)((const char*)Pw + ln15 * 128 +                 \
                             ((64 + lg * 16) ^ ((ln15 & 7) << 4)));         \
    _Pragma("unroll") for (int ks = 0; ks < 2; ++ks)                        \
      _Pragma("unroll") for (int dt = 0; dt < 4; ++dt)                      \
        accO[dt] = __builtin_amdgcn_mfma_f32_16x16x32_bf16(                 \
            vfr[ks * 4 + dt], pt[ks], accO[dt], 0, 0, 0);                   \
  } while (0)

#define BODY_PF(RC1, RC2, RN1, RN2, KT) do {                                \
    bf16x8 kfr[8], vfr[8];                                                  \
    LOAD_K(kfr, (KT) * 64);                                                 \
    LOAD_V(vfr, (KT) * 64);                                                 \
    __builtin_amdgcn_sched_barrier(0);                                      \
    LOAD_REL(RN1, RN2, ((KT) + 1) * 64);                                    \
    __builtin_amdgcn_sched_barrier(0);                                      \
    COMPUTE(RC1, RC2, KT);                                                  \
  } while (0)

#define BODY_NP(RC1, RC2, KT) do {                                          \
    bf16x8 kfr[8], vfr[8];                                                  \
    LOAD_K(kfr, (KT) * 64);                                                 \
    LOAD_V(vfr, (KT) * 64);                                                 \
    __builtin_amdgcn_sched_barrier(0);                                      \
    COMPUTE(RC1, RC2, KT);                                                  \
  } while (0)

  float4 r1a[4], r2a[4], r1b[4], r2b[4];

  LOAD_REL(r1a, r2a, 0);
  __builtin_amdgcn_sched_barrier(0);

  for (int t = 0; t < 7; ++t) {
    BODY_PF(r1a, r2a, r1b, r2b, 2 * t);
    BODY_PF(r1b, r2b, r1a, r2a, 2 * t + 1);
  }
  BODY_PF(r1a, r2a, r1b, r2b, 14);
  BODY_NP(r1b, r2b, 15);

  // epilogue: lane holds ctx^T[d=dt*16+lg*4+j][q=q0+ln15]; out fp32 [b,s,C]
  float rl = 1.0f / lrun;
#pragma unroll
  for (int dt = 0; dt < 4; ++dt) {
    float4 o;
    o.x = accO[dt][0] * rl;
    o.y = accO[dt][1] * rl;
    o.z = accO[dt][2] * rl;
    o.w = accO[dt][3] * rl;
    *(float4*)&out[((size_t)(b * 1024 + q0 + ln15)) * 1024 + h * 64 +
                   dt * 16 + lg * 4] = o;
  }
}

// ---------------------------------------------------------------------------
extern "C" void kernel_launch(void* const* d_in, const int* in_sizes, int n_in,
                              void* d_out, int out_size, void* d_ws,
                              size_t ws_size, hipStream_t stream) {
  const float* hs   = (const float*)d_in[0];
  const float* mask = (const float*)d_in[1];
  const float* rel1 = (const float*)d_in[2];
  const float* rel2 = (const float*)d_in[3];
  const float* Wq   = (const float*)d_in[4];
  const float* bq   = (const float*)d_in[5];
  const float* Wk   = (const float*)d_in[6];
  const float* bk   = (const float*)d_in[7];
  const float* Wv   = (const float*)d_in[8];
  const float* bv   = (const float*)d_in[9];

  char* ws = (char*)d_ws;
  __hip_bfloat16* hbf = (__hip_bfloat16*)(ws);              // 8 MB
  __hip_bfloat16* wbf = (__hip_bfloat16*)(ws + 8388608);    // 6 MB
  __hip_bfloat16* qb  = (__hip_bfloat16*)(ws + 14680064);   // 8 MB
  __hip_bfloat16* kb  = (__hip_bfloat16*)(ws + 23068672);   // 8 MB
  __hip_bfloat16* vtb = (__hip_bfloat16*)(ws + 31457280);   // 8 MB (total 38)

  cvt_kernel<<<7168, 256, 0, stream>>>(hs, Wq, Wk, Wv, hbf, wbf);
  qkv_gemm<<<768, 256, 0, stream>>>(hbf, wbf, bq, bk, bv, qb, kb, vtb);
  attn_kernel<<<1024, 256, 0, stream>>>(qb, kb, vtb, rel1, rel2, mask,
                                        (float*)d_out);
}

// Round 6
// 218.458 us; speedup vs baseline: 1.5333x; 1.1181x over previous
//
#include <hip/hip_runtime.h>
#include <hip/hip_bf16.h>

typedef __attribute__((ext_vector_type(8))) short bf16x8;
typedef __attribute__((ext_vector_type(4))) float f32x4;

#define LDSG(g, l) __builtin_amdgcn_global_load_lds(                      \
    (const __attribute__((address_space(1))) void*)(g),                   \
    (__attribute__((address_space(3))) void*)(l), 16, 0, 0)

#define LOG2E 1.44269504088896f
#define RELSC 0.180336880111112f   /* 0.125 * log2(e) */

// ---------------- kernel 1: fp32 -> bf16 convert (hidden + Wq|Wk|Wv) --------
__global__ __launch_bounds__(256) void cvt_kernel(
    const float* __restrict__ hs,
    const float* __restrict__ wq, const float* __restrict__ wk,
    const float* __restrict__ wv,
    __hip_bfloat16* __restrict__ hbf, __hip_bfloat16* __restrict__ wbf)
{
  const int NH = (4 * 1024 * 1024) / 4;   // hidden quads
  const int NW = (1024 * 1024) / 4;       // per-W quads
  int i = blockIdx.x * 256 + threadIdx.x; // exact grid: NH + 3*NW quads
  float4 v;
  __hip_bfloat16* dst;
  if (i < NH) {
    v = ((const float4*)hs)[i];
    dst = hbf + (size_t)i * 4;
  } else {
    int j = i - NH;
    int which = j / NW, r = j - which * NW;
    const float* src = which == 0 ? wq : (which == 1 ? wk : wv);
    v = ((const float4*)src)[r];
    dst = wbf + (size_t)j * 4;
  }
  union { ushort4 u; __hip_bfloat16 b[4]; } o;
  o.b[0] = __float2bfloat16(v.x);
  o.b[1] = __float2bfloat16(v.y);
  o.b[2] = __float2bfloat16(v.z);
  o.b[3] = __float2bfloat16(v.w);
  *((ushort4*)dst) = o.u;
}

// ---------------- kernel 2: QKV GEMM  C[4096][3072] = A[4096][1024] @ W^T ---
// q scaled by 0.125*log2e and stored [b,h,s,d]; k stored [b,h,s,d];
// v stored TRANSPOSED [b,h,d,s] so attention reads V^T fragments directly.
__global__ __launch_bounds__(256) void qkv_gemm(
    const __hip_bfloat16* __restrict__ A,  // [4096][1024]
    const __hip_bfloat16* __restrict__ W,  // [3072][1024] (q,k,v stacked)
    const float* __restrict__ bq, const float* __restrict__ bk,
    const float* __restrict__ bv,
    __hip_bfloat16* __restrict__ qo, __hip_bfloat16* __restrict__ ko,
    __hip_bfloat16* __restrict__ vo)
{
  const int K = 1024;
  __shared__ __hip_bfloat16 As[128 * 64];
  __shared__ __hip_bfloat16 Bs[128 * 64];
  const int bid = blockIdx.x;
  const int bm = bid & 31, bn = bid >> 5;
  const int m0 = bm * 128, n0 = bn * 128;
  const int tid = threadIdx.x, wid = tid >> 6, lane = tid & 63;
  const int wm = wid >> 1, wn = wid & 1;

  f32x4 acc[4][4] = {};

  const int srow = lane >> 3;              // 0..7 (row within 8-row group)
  const int schunk = (lane & 7) ^ srow;    // swizzled 16B-chunk in row

  for (int k0 = 0; k0 < K; k0 += 64) {
#pragma unroll
    for (int p = 0; p < 4; ++p) {
      int r = (wid * 4 + p) * 8 + srow;    // 0..127
      LDSG(&A[(size_t)(m0 + r) * K + k0 + schunk * 8], &As[(wid * 4 + p) * 512]);
      LDSG(&W[(size_t)(n0 + r) * K + k0 + schunk * 8], &Bs[(wid * 4 + p) * 512]);
    }
    __syncthreads();
#pragma unroll
    for (int ks = 0; ks < 2; ++ks) {
      bf16x8 af[4], bfr[4];
#pragma unroll
      for (int mi = 0; mi < 4; ++mi) {
        int row = wm * 64 + mi * 16 + (lane & 15);
        int slot = (ks * 4 + (lane >> 4)) ^ (lane & 7);
        af[mi] = *(const bf16x8*)((const char*)As + row * 128 + slot * 16);
      }
#pragma unroll
      for (int ni = 0; ni < 4; ++ni) {
        int row = wn * 64 + ni * 16 + (lane & 15);
        int slot = (ks * 4 + (lane >> 4)) ^ (lane & 7);
        bfr[ni] = *(const bf16x8*)((const char*)Bs + row * 128 + slot * 16);
      }
#pragma unroll
      for (int mi = 0; mi < 4; ++mi)
#pragma unroll
        for (int ni = 0; ni < 4; ++ni)
          acc[mi][ni] = __builtin_amdgcn_mfma_f32_16x16x32_bf16(
              af[mi], bfr[ni], acc[mi][ni], 0, 0, 0);
    }
    __syncthreads();
  }

  // epilogue. C/D layout: col = lane&15, row = (lane>>4)*4+j.
#pragma unroll
  for (int ni = 0; ni < 4; ++ni) {
    int n = n0 + wn * 64 + ni * 16 + (lane & 15);
    int which = n >> 10;         // 0=q 1=k 2=v (uniform per block)
    int h = (n >> 6) & 15;
    int d = n & 63;
    const float* bias = which == 0 ? bq : (which == 1 ? bk : bv);
    float bval = bias[n & 1023];
    if (which == 2) {
      // v transposed: vo[(bh*64+d)*1024 + s], 4 consecutive s -> ushort4
#pragma unroll
      for (int mi = 0; mi < 4; ++mi) {
        int m = m0 + wm * 64 + mi * 16 + (lane >> 4) * 4;
        int b = m >> 10, s = m & 1023;
        union { ushort4 u; __hip_bfloat16 bb[4]; } o;
#pragma unroll
        for (int j = 0; j < 4; ++j)
          o.bb[j] = __float2bfloat16(acc[mi][ni][j] + bval);
        *(ushort4*)&vo[((size_t)((b * 16 + h) * 64 + d) << 10) + s] = o.u;
      }
    } else {
      __hip_bfloat16* dst = which == 0 ? qo : ko;
      float scale = (which == 0) ? RELSC : 1.0f; // q pre-scaled by inv_sqrt_d*log2e
#pragma unroll
      for (int mi = 0; mi < 4; ++mi) {
#pragma unroll
        for (int j = 0; j < 4; ++j) {
          int m = m0 + wm * 64 + mi * 16 + (lane >> 4) * 4 + j;
          int b = m >> 10, s = m & 1023;
          float val = (acc[mi][ni][j] + bval) * scale;
          dst[(((size_t)(b * 16 + h) << 10) + s) * 64 + d] = __float2bfloat16(val);
        }
      }
    }
  }
}

// ---------------- kernel 3: flash attention, contiguous rel via LDSG --------
// grid 1024 = 64 bh x 16 q-tiles of 64 rows; 4 waves/block, wave owns 16 q.
// rel1/rel2 staged to wave-private LDS via global_load_lds where each wave
// instruction covers 4 rows x 256 B CONTIGUOUS (lane = row x 16B-chunk),
// with the fragment-read bank conflict removed by pre-swizzling the GLOBAL
// chunk (chunk ^= row&7; LDS dest stays linear — m173 pattern).
// Per body, issue order [K(t) regs, V(t) regs, STAGE_rel(t+1)]:
//   QK^T auto-waits vmcnt(16) (drains K, keeps V+STAGE in flight),
//   rel ds_read after explicit vmcnt(16), PV auto-waits vmcnt(8) (keeps
//   STAGE(t+1) in flight) -> rel stream always a full body ahead. No
//   barriers in the loop (rel buffers are wave-private).
__global__ __launch_bounds__(256, 2) void attn_kernel(
    const __hip_bfloat16* __restrict__ qg, const __hip_bfloat16* __restrict__ kg,
    const __hip_bfloat16* __restrict__ vtg,
    const float* __restrict__ rel1, const float* __restrict__ rel2,
    const float* __restrict__ mask, float* __restrict__ out)
{
  __shared__ float Rbuf[4][2][2][16][64];   // [wave][buf][rel][row][k] 64 KB
  __shared__ float Ml[1024];                // mask * log2e, 4 KB
  __shared__ __hip_bfloat16 Ps[4][16 * 64]; // P transpose bounce, 8 KB

  const int bid = blockIdx.x;
  const int bh = bid & 63, qt = bid >> 6;   // bid%8==bh%8 -> bh pinned to XCD
  const int b = bh >> 4, h = bh & 15;
  const int tid = threadIdx.x, wid = tid >> 6, lane = tid & 63;
  const int lg = lane >> 4, ln15 = lane & 15;
  const int r4 = lane >> 4, c15 = lane & 15;

  const size_t kvbase = (size_t)bh << 16;
  const int q0 = qt * 64 + wid * 16;

  // stage mask (pre-scaled by log2e) into LDS once
  {
    float4 mv = *(const float4*)&mask[((size_t)b << 10) + tid * 4];
    float4 sm;
    sm.x = mv.x * LOG2E; sm.y = mv.y * LOG2E;
    sm.z = mv.z * LOG2E; sm.w = mv.w * LOG2E;
    *(float4*)&Ml[tid * 4] = sm;
  }
  __syncthreads();

  // Q as B-operand fragment: col=ln15=q, contraction d = ks*32 + lg*8 + jj
  bf16x8 qf[2];
  qf[0] = *(const bf16x8*)&qg[kvbase + (size_t)(q0 + ln15) * 64 + lg * 8];
  qf[1] = *(const bf16x8*)&qg[kvbase + (size_t)(q0 + ln15) * 64 + 32 + lg * 8];

  f32x4 accO[4] = {};
  float mrun = -1e30f, lrun = 0.f;

  const float* relw1 = rel1 + ((size_t)bh << 20);
  const float* relw2 = rel2 + ((size_t)bh << 20);

  // Each LDSG: 64 lanes x 16B = 4 rows x 256B contiguous global footprint.
  // lane L: row rg = 4p + (L>>4), global chunk cg = (L&15) ^ (rg&7);
  // LDS[rg][chunk c] = G[rg][c ^ (rg&7)].
#define STAGE_REL(BUF, KB) do {                                             \
    _Pragma("unroll") for (int p = 0; p < 4; ++p) {                         \
      int rg = 4 * p + r4;                                                  \
      int cg = c15 ^ (rg & 7);                                              \
      LDSG(&relw1[(size_t)(q0 + rg) * 1024 + (KB) + cg * 4],                \
           &Rbuf[wid][BUF][0][4 * p][0]);                                   \
      LDSG(&relw2[(size_t)(q0 + rg) * 1024 + (KB) + cg * 4],                \
           &Rbuf[wid][BUF][1][4 * p][0]);                                   \
    } } while (0)

#define LOAD_K(KF, KBO) do {                                                \
    _Pragma("unroll") for (int ks = 0; ks < 2; ++ks)                        \
      _Pragma("unroll") for (int ct = 0; ct < 4; ++ct)                      \
        KF[ks * 4 + ct] = *(const bf16x8*)&kg[kvbase +                      \
            (size_t)((KBO) + ct * 16 + ln15) * 64 + ks * 32 + lg * 8];      \
    } while (0)

#define LOAD_V(VF, KBO) do {                                                \
    _Pragma("unroll") for (int ks = 0; ks < 2; ++ks)                        \
      _Pragma("unroll") for (int dt = 0; dt < 4; ++dt)                      \
        VF[ks * 4 + dt] = *(const bf16x8*)&vtg[kvbase +                     \
            (size_t)(dt * 16 + ln15) * 1024 + (KBO) + ks * 32 + lg * 8];    \
    } while (0)

#define BODY(BUF, KT, DO_STAGE) do {                                        \
    bf16x8 kfr[8], vfr[8];                                                  \
    LOAD_K(kfr, (KT) * 64);                                                 \
    LOAD_V(vfr, (KT) * 64);                                                 \
    __builtin_amdgcn_sched_barrier(0);                                      \
    if (DO_STAGE) STAGE_REL((BUF) ^ 1, ((KT) + 1) * 64);                    \
    __builtin_amdgcn_sched_barrier(0);                                      \
    f32x4 st[4] = {};                                                       \
    _Pragma("unroll") for (int ks = 0; ks < 2; ++ks)                        \
      _Pragma("unroll") for (int ct = 0; ct < 4; ++ct)                      \
        st[ct] = __builtin_amdgcn_mfma_f32_16x16x32_bf16(                   \
            kfr[ks * 4 + ct], qf[ks], st[ct], 0, 0, 0);                     \
    asm volatile("s_waitcnt vmcnt(16)" ::: "memory");                       \
    __builtin_amdgcn_sched_barrier(0);                                      \
    float p[4][4]; float mt = -1e30f;                                       \
    _Pragma("unroll") for (int ct = 0; ct < 4; ++ct) {                      \
      int cc = ((ct * 4 + lg) ^ (ln15 & 7)) * 16;                           \
      float4 rv1 = *(const float4*)((const char*)&Rbuf[wid][BUF][0][0][0] + \
                                    ln15 * 256 + cc);                       \
      float4 rv2 = *(const float4*)((const char*)&Rbuf[wid][BUF][1][0][0] + \
                                    ln15 * 256 + cc);                       \
      float4 mv = *(const float4*)&Ml[(KT) * 64 + ct * 16 + lg * 4];        \
      _Pragma("unroll") for (int j = 0; j < 4; ++j) {                       \
        float sv = st[ct][j] +                                              \
                   RELSC * (((const float*)&rv1)[j] +                       \
                            ((const float*)&rv2)[j]) +                      \
                   ((const float*)&mv)[j];                                  \
        p[ct][j] = sv; mt = fmaxf(mt, sv);                                  \
      }                                                                     \
    }                                                                       \
    mt = fmaxf(mt, __shfl_xor(mt, 16, 64));                                 \
    mt = fmaxf(mt, __shfl_xor(mt, 32, 64));                                 \
    float mnew = fmaxf(mrun, mt);                                           \
    float sc_ = __builtin_amdgcn_exp2f(mrun - mnew);                        \
    mrun = mnew;                                                            \
    float lsum = 0.f;                                                       \
    _Pragma("unroll") for (int ct = 0; ct < 4; ++ct)                        \
      _Pragma("unroll") for (int j = 0; j < 4; ++j) {                       \
        float e = __builtin_amdgcn_exp2f(p[ct][j] - mnew);                  \
        p[ct][j] = e; lsum += e;                                            \
      }                                                                     \
    lsum += __shfl_xor(lsum, 16, 64);                                       \
    lsum += __shfl_xor(lsum, 32, 64);                                       \
    lrun = lrun * sc_ + lsum;                                               \
    _Pragma("unroll") for (int dt = 0; dt < 4; ++dt) accO[dt] *= sc_;       \
    __hip_bfloat16* Pw = &Ps[wid][0];                                       \
    _Pragma("unroll") for (int ct = 0; ct < 4; ++ct) {                      \
      union { ushort4 u; __hip_bfloat16 bb[4]; } w;                         \
      _Pragma("unroll") for (int j = 0; j < 4; ++j)                         \
        w.bb[j] = __float2bfloat16(p[ct][j]);                               \
      *(ushort4*)((char*)Pw + ln15 * 128 +                                  \
                  ((ct * 32 + lg * 8) ^ ((ln15 & 7) << 4))) = w.u;          \
    }                                                                       \
    bf16x8 pt[2];                                                           \
    pt[0] = *(const bf16x8*)((const char*)Pw + ln15 * 128 +                 \
                             ((lg * 16) ^ ((ln15 & 7) << 4)));              \
    pt[1] = *(const bf16x8*)((const char*)Pw + ln15 * 128 +                 \
                             ((64 + lg * 16) ^ ((ln15 & 7) << 4)));         \
    _Pragma("unroll") for (int ks = 0; ks < 2; ++ks)                        \
      _Pragma("unroll") for (int dt = 0; dt < 4; ++dt)                      \
        accO[dt] = __builtin_amdgcn_mfma_f32_16x16x32_bf16(                 \
            vfr[ks * 4 + dt], pt[ks], accO[dt], 0, 0, 0);                   \
  } while (0)

  STAGE_REL(0, 0);

  for (int t = 0; t < 7; ++t) {
    BODY(0, 2 * t, 1);
    BODY(1, 2 * t + 1, 1);
  }
  BODY(0, 14, 1);
  BODY(1, 15, 0);

  // epilogue: lane holds ctx^T[d=dt*16+lg*4+j][q=q0+ln15]; out fp32 [b,s,C]
  float rl = 1.0f / lrun;
#pragma unroll
  for (int dt = 0; dt < 4; ++dt) {
    float4 o;
    o.x = accO[dt][0] * rl;
    o.y = accO[dt][1] * rl;
    o.z = accO[dt][2] * rl;
    o.w = accO[dt][3] * rl;
    *(float4*)&out[((size_t)(b * 1024 + q0 + ln15)) * 1024 + h * 64 +
                   dt * 16 + lg * 4] = o;
  }
}

// ---------------------------------------------------------------------------
extern "C" void kernel_launch(void* const* d_in, const int* in_sizes, int n_in,
                              void* d_out, int out_size, void* d_ws,
                              size_t ws_size, hipStream_t stream) {
  const float* hs   = (const float*)d_in[0];
  const float* mask = (const float*)d_in[1];
  const float* rel1 = (const float*)d_in[2];
  const float* rel2 = (const float*)d_in[3];
  const float* Wq   = (const float*)d_in[4];
  const float* bq   = (const float*)d_in[5];
  const float* Wk   = (const float*)d_in[6];
  const float* bk   = (const float*)d_in[7];
  const float* Wv   = (const float*)d_in[8];
  const float* bv   = (const float*)d_in[9];

  char* ws = (char*)d_ws;
  __hip_bfloat16* hbf = (__hip_bfloat16*)(ws);              // 8 MB
  __hip_bfloat16* wbf = (__hip_bfloat16*)(ws + 8388608);    // 6 MB
  __hip_bfloat16* qb  = (__hip_bfloat16*)(ws + 14680064);   // 8 MB
  __hip_bfloat16* kb  = (__hip_bfloat16*)(ws + 23068672);   // 8 MB
  __hip_bfloat16* vtb = (__hip_bfloat16*)(ws + 31457280);   // 8 MB (total 38)

  cvt_kernel<<<7168, 256, 0, stream>>>(hs, Wq, Wk, Wv, hbf, wbf);
  qkv_gemm<<<768, 256, 0, stream>>>(hbf, wbf, bq, bk, bv, qb, kb, vtb);
  attn_kernel<<<1024, 256, 0, stream>>>(qb, kb, vtb, rel1, rel2, mask,
                                        (float*)d_out);
}

// Round 7
// 200.681 us; speedup vs baseline: 1.6692x; 1.0886x over previous
//
#include <hip/hip_runtime.h>
#include <hip/hip_bf16.h>

typedef __attribute__((ext_vector_type(8))) short bf16x8;
typedef __attribute__((ext_vector_type(4))) float f32x4;

#define LDSG(g, l) __builtin_amdgcn_global_load_lds(                      \
    (const __attribute__((address_space(1))) void*)(g),                   \
    (__attribute__((address_space(3))) void*)(l), 16, 0, 0)

#define LOG2E 1.44269504088896f
#define RELSC 0.180336880111112f   /* 0.125 * log2(e) */

// ---------------- kernel 1: fp32 -> bf16 convert (hidden + Wq|Wk|Wv) --------
__global__ __launch_bounds__(256) void cvt_kernel(
    const float* __restrict__ hs,
    const float* __restrict__ wq, const float* __restrict__ wk,
    const float* __restrict__ wv,
    __hip_bfloat16* __restrict__ hbf, __hip_bfloat16* __restrict__ wbf)
{
  const int NH = (4 * 1024 * 1024) / 4;   // hidden quads
  const int NW = (1024 * 1024) / 4;       // per-W quads
  int i = blockIdx.x * 256 + threadIdx.x; // exact grid: NH + 3*NW quads
  float4 v;
  __hip_bfloat16* dst;
  if (i < NH) {
    v = ((const float4*)hs)[i];
    dst = hbf + (size_t)i * 4;
  } else {
    int j = i - NH;
    int which = j / NW, r = j - which * NW;
    const float* src = which == 0 ? wq : (which == 1 ? wk : wv);
    v = ((const float4*)src)[r];
    dst = wbf + (size_t)j * 4;
  }
  union { ushort4 u; __hip_bfloat16 b[4]; } o;
  o.b[0] = __float2bfloat16(v.x);
  o.b[1] = __float2bfloat16(v.y);
  o.b[2] = __float2bfloat16(v.z);
  o.b[3] = __float2bfloat16(v.w);
  *((ushort4*)dst) = o.u;
}

// ---------------- kernel 2: QKV GEMM  C[4096][3072] = A[4096][1024] @ W^T ---
// q scaled by 0.125*log2e, stored [b,h,s,d].
// k/v written PRE-FRAGMENTED in MFMA A-operand order per (bh, ktile):
//   K  chunk (ks*4+ct)*64+lane holds K[k=ct*16+(lane&15)][d=ks*32+(lane>>4)*8+e]
//   V^T chunk (ks*4+dt)*64+lane holds V[k=ks*32+(lane>>4)*8+e][d=dt*16+(lane&15)]
// so attention loads are fully contiguous 1KB instructions.
__global__ __launch_bounds__(256) void qkv_gemm(
    const __hip_bfloat16* __restrict__ A,  // [4096][1024]
    const __hip_bfloat16* __restrict__ W,  // [3072][1024] (q,k,v stacked)
    const float* __restrict__ bq, const float* __restrict__ bk,
    const float* __restrict__ bv,
    __hip_bfloat16* __restrict__ qo, __hip_bfloat16* __restrict__ ko,
    __hip_bfloat16* __restrict__ vo)
{
  const int K = 1024;
  __shared__ __hip_bfloat16 As[128 * 64];
  __shared__ __hip_bfloat16 Bs[128 * 64];
  const int bid = blockIdx.x;
  const int bm = bid & 31, bn = bid >> 5;
  const int m0 = bm * 128, n0 = bn * 128;
  const int tid = threadIdx.x, wid = tid >> 6, lane = tid & 63;
  const int wm = wid >> 1, wn = wid & 1;

  f32x4 acc[4][4] = {};

  const int srow = lane >> 3;              // 0..7 (row within 8-row group)
  const int schunk = (lane & 7) ^ srow;    // swizzled 16B-chunk in row

  for (int k0 = 0; k0 < K; k0 += 64) {
#pragma unroll
    for (int p = 0; p < 4; ++p) {
      int r = (wid * 4 + p) * 8 + srow;    // 0..127
      LDSG(&A[(size_t)(m0 + r) * K + k0 + schunk * 8], &As[(wid * 4 + p) * 512]);
      LDSG(&W[(size_t)(n0 + r) * K + k0 + schunk * 8], &Bs[(wid * 4 + p) * 512]);
    }
    __syncthreads();
#pragma unroll
    for (int ks = 0; ks < 2; ++ks) {
      bf16x8 af[4], bfr[4];
#pragma unroll
      for (int mi = 0; mi < 4; ++mi) {
        int row = wm * 64 + mi * 16 + (lane & 15);
        int slot = (ks * 4 + (lane >> 4)) ^ (lane & 7);
        af[mi] = *(const bf16x8*)((const char*)As + row * 128 + slot * 16);
      }
#pragma unroll
      for (int ni = 0; ni < 4; ++ni) {
        int row = wn * 64 + ni * 16 + (lane & 15);
        int slot = (ks * 4 + (lane >> 4)) ^ (lane & 7);
        bfr[ni] = *(const bf16x8*)((const char*)Bs + row * 128 + slot * 16);
      }
#pragma unroll
      for (int mi = 0; mi < 4; ++mi)
#pragma unroll
        for (int ni = 0; ni < 4; ++ni)
          acc[mi][ni] = __builtin_amdgcn_mfma_f32_16x16x32_bf16(
              af[mi], bfr[ni], acc[mi][ni], 0, 0, 0);
    }
    __syncthreads();
  }

  // epilogue. C/D layout: col = lane&15, row = (lane>>4)*4+j.
#pragma unroll
  for (int ni = 0; ni < 4; ++ni) {
    int n = n0 + wn * 64 + ni * 16 + (lane & 15);
    int which = n >> 10;         // 0=q 1=k 2=v (uniform per block)
    int h = (n >> 6) & 15;
    int d = n & 63;
    const float* bias = which == 0 ? bq : (which == 1 ? bk : bv);
    float bval = bias[n & 1023];
    if (which == 0) {
      // q: [b,h,s,d], pre-scaled by 0.125*log2e
#pragma unroll
      for (int mi = 0; mi < 4; ++mi) {
#pragma unroll
        for (int j = 0; j < 4; ++j) {
          int m = m0 + wm * 64 + mi * 16 + (lane >> 4) * 4 + j;
          int b = m >> 10, s = m & 1023;
          float val = (acc[mi][ni][j] + bval) * RELSC;
          qo[(((size_t)(b * 16 + h) << 10) + s) * 64 + d] = __float2bfloat16(val);
        }
      }
    } else if (which == 1) {
      // K fragment store (scalar scatter)
      int dks = d >> 5, dlg = (d >> 3) & 3, de = d & 7;
#pragma unroll
      for (int mi = 0; mi < 4; ++mi) {
#pragma unroll
        for (int j = 0; j < 4; ++j) {
          int m = m0 + wm * 64 + mi * 16 + (lane >> 4) * 4 + j;
          int b = m >> 10, s = m & 1023;
          size_t idx = ((((size_t)(b * 16 + h)) * 16 + (s >> 6)) * 512 +
                        (size_t)((dks * 4 + ((s >> 4) & 3)) * 64 + (s & 15) +
                                 16 * dlg)) * 8 + de;
          ko[idx] = __float2bfloat16(acc[mi][ni][j] + bval);
        }
      }
    } else {
      // V^T fragment store (ushort4: 4 consecutive k -> consecutive e)
      int dt = d >> 4, dl15 = d & 15;
#pragma unroll
      for (int mi = 0; mi < 4; ++mi) {
        int m = m0 + wm * 64 + mi * 16 + (lane >> 4) * 4;  // k0 (mod 4 == 0)
        int b = m >> 10, k = m & 1023;
        int kt = k >> 6, kks = (k >> 5) & 1, klg = (k >> 3) & 3, ke = k & 7;
        union { ushort4 u; __hip_bfloat16 bb[4]; } o;
#pragma unroll
        for (int j = 0; j < 4; ++j)
          o.bb[j] = __float2bfloat16(acc[mi][ni][j] + bval);
        size_t idx = ((((size_t)(b * 16 + h)) * 16 + kt) * 512 +
                      (size_t)((kks * 4 + dt) * 64 + dl15 + 16 * klg)) * 8 + ke;
        *(ushort4*)&vo[idx] = o.u;
      }
    }
  }
}

// ---------------- kernel 3: flash attention, fixed-max + fragment K/V -------
// grid 1024 = 64 bh x 16 q-tiles of 64 rows; 4 waves/block own 16 q-rows each.
// K/V^T read from pre-fragmented layout: 8 contiguous 1KB loads per tile.
// Fixed-max softmax: Ml = mask*log2e - 32; p = exp2(s - 32); no running max,
// no rescale, lane-local denominator reduced once after the loop.
// rel staged via LDSG->LDS dbuf (256B-contiguous segments, XOR pre-swizzle).
// No barriers in the loop (all LDS wave-private after mask stage).
__global__ __launch_bounds__(256, 2) void attn_kernel(
    const __hip_bfloat16* __restrict__ qg, const __hip_bfloat16* __restrict__ kf,
    const __hip_bfloat16* __restrict__ vf,
    const float* __restrict__ rel1, const float* __restrict__ rel2,
    const float* __restrict__ mask, float* __restrict__ out)
{
  __shared__ float Rbuf[4][2][2][16][64];   // [wave][buf][rel][row][k] 64 KB
  __shared__ float Ml[1024];                // mask*log2e - 32, 4 KB
  __shared__ __hip_bfloat16 Ps[4][16 * 64]; // P transpose bounce, 8 KB

  const int bid = blockIdx.x;
  const int bh = bid & 63, qt = bid >> 6;   // bid%8==bh%8 -> bh pinned to XCD
  const int b = bh >> 4, h = bh & 15;
  const int tid = threadIdx.x, wid = tid >> 6, lane = tid & 63;
  const int lg = lane >> 4, ln15 = lane & 15;
  const int r4 = lane >> 4, c15 = lane & 15;

  const size_t qbase = (size_t)bh << 16;    // bh * 1024 * 64
  const size_t fbase = (size_t)bh << 16;    // 65536 bf16 elems per bh (frag)
  const int q0 = qt * 64 + wid * 16;

  // stage mask: Ml = mask*log2e - 32 (the -32 is the fixed softmax max)
  {
    float4 mv = *(const float4*)&mask[((size_t)b << 10) + tid * 4];
    float4 sm;
    sm.x = mv.x * LOG2E - 32.0f; sm.y = mv.y * LOG2E - 32.0f;
    sm.z = mv.z * LOG2E - 32.0f; sm.w = mv.w * LOG2E - 32.0f;
    *(float4*)&Ml[tid * 4] = sm;
  }
  __syncthreads();

  // Q as B-operand fragment: col=ln15=q, contraction d = ks*32 + lg*8 + jj
  bf16x8 qf[2];
  qf[0] = *(const bf16x8*)&qg[qbase + (size_t)(q0 + ln15) * 64 + lg * 8];
  qf[1] = *(const bf16x8*)&qg[qbase + (size_t)(q0 + ln15) * 64 + 32 + lg * 8];

  f32x4 accO[4] = {};
  float lrun = 0.f;

  const float* relw1 = rel1 + ((size_t)bh << 20);
  const float* relw2 = rel2 + ((size_t)bh << 20);

#define STAGE_REL(BUF, KB) do {                                             \
    _Pragma("unroll") for (int p = 0; p < 4; ++p) {                         \
      int rg = 4 * p + r4;                                                  \
      int cg = c15 ^ (rg & 7);                                              \
      LDSG(&relw1[(size_t)(q0 + rg) * 1024 + (KB) + cg * 4],                \
           &Rbuf[wid][BUF][0][4 * p][0]);                                   \
      LDSG(&relw2[(size_t)(q0 + rg) * 1024 + (KB) + cg * 4],                \
           &Rbuf[wid][BUF][1][4 * p][0]);                                   \
    } } while (0)

  // fragment loads: 8 x contiguous 1KB per tile
#define LOAD_K(KF_, KT) do {                                                \
    _Pragma("unroll") for (int i = 0; i < 8; ++i)                           \
      KF_[i] = *(const bf16x8*)&kf[fbase + (size_t)(KT) * 4096 + i * 512 +  \
                                   lane * 8];                               \
    } while (0)

#define LOAD_V(VF_, KT) do {                                                \
    _Pragma("unroll") for (int i = 0; i < 8; ++i)                           \
      VF_[i] = *(const bf16x8*)&vf[fbase + (size_t)(KT) * 4096 + i * 512 +  \
                                   lane * 8];                               \
    } while (0)

#define BODY(BUF, KT, DO_STAGE) do {                                        \
    bf16x8 kfr[8], vfr[8];                                                  \
    LOAD_K(kfr, KT);                                                        \
    LOAD_V(vfr, KT);                                                        \
    __builtin_amdgcn_sched_barrier(0);                                      \
    if (DO_STAGE) STAGE_REL((BUF) ^ 1, ((KT) + 1) * 64);                    \
    __builtin_amdgcn_sched_barrier(0);                                      \
    f32x4 st[4] = {};                                                       \
    _Pragma("unroll") for (int ks = 0; ks < 2; ++ks)                        \
      _Pragma("unroll") for (int ct = 0; ct < 4; ++ct)                      \
        st[ct] = __builtin_amdgcn_mfma_f32_16x16x32_bf16(                   \
            kfr[ks * 4 + ct], qf[ks], st[ct], 0, 0, 0);                     \
    asm volatile("s_waitcnt vmcnt(16)" ::: "memory");                       \
    __builtin_amdgcn_sched_barrier(0);                                      \
    float p[4][4];                                                          \
    _Pragma("unroll") for (int ct = 0; ct < 4; ++ct) {                      \
      int cc = ((ct * 4 + lg) ^ (ln15 & 7)) * 16;                           \
      float4 rv1 = *(const float4*)((const char*)&Rbuf[wid][BUF][0][0][0] + \
                                    ln15 * 256 + cc);                       \
      float4 rv2 = *(const float4*)((const char*)&Rbuf[wid][BUF][1][0][0] + \
                                    ln15 * 256 + cc);                       \
      float4 mv = *(const float4*)&Ml[(KT) * 64 + ct * 16 + lg * 4];        \
      _Pragma("unroll") for (int j = 0; j < 4; ++j) {                       \
        float sv = st[ct][j] +                                              \
                   RELSC * (((const float*)&rv1)[j] +                       \
                            ((const float*)&rv2)[j]) +                      \
                   ((const float*)&mv)[j];                                  \
        float e = __builtin_amdgcn_exp2f(sv);                               \
        p[ct][j] = e; lrun += e;                                            \
      }                                                                     \
    }                                                                       \
    __hip_bfloat16* Pw = &Ps[wid][0];                                       \
    _Pragma("unroll") for (int ct = 0; ct < 4; ++ct) {                      \
      union { ushort4 u; __hip_bfloat16 bb[4]; } w;                         \
      _Pragma("unroll") for (int j = 0; j < 4; ++j)                         \
        w.bb[j] = __float2bfloat16(p[ct][j]);                               \
      *(ushort4*)((char*)Pw + ln15 * 128 +                                  \
                  ((ct * 32 + lg * 8) ^ ((ln15 & 7) << 4))) = w.u;          \
    }                                                                       \
    bf16x8 pt[2];                                                           \
    pt[0] = *(const bf16x8*)((const char*)Pw + ln15 * 128 +                 \
                             ((lg * 16) ^ ((ln15 & 7) << 4)));              \
    pt[1] = *(const bf16x8*)((const char*)Pw + ln15 * 128 +                 \
                             ((64 + lg * 16) ^ ((ln15 & 7) << 4)));         \
    _Pragma("unroll") for (int ks = 0; ks < 2; ++ks)                        \
      _Pragma("unroll") for (int dt = 0; dt < 4; ++dt)                      \
        accO[dt] = __builtin_amdgcn_mfma_f32_16x16x32_bf16(                 \
            vfr[ks * 4 + dt], pt[ks], accO[dt], 0, 0, 0);                   \
  } while (0)

  STAGE_REL(0, 0);

  for (int t = 0; t < 7; ++t) {
    BODY(0, 2 * t, 1);
    BODY(1, 2 * t + 1, 1);
  }
  BODY(0, 14, 1);
  BODY(1, 15, 0);

  // single final denominator reduce (q = ln15 column preserved)
  lrun += __shfl_xor(lrun, 16, 64);
  lrun += __shfl_xor(lrun, 32, 64);
  float rl = 1.0f / lrun;

  // epilogue: lane holds ctx^T[d=dt*16+lg*4+j][q=q0+ln15]; out fp32 [b,s,C]
#pragma unroll
  for (int dt = 0; dt < 4; ++dt) {
    float4 o;
    o.x = accO[dt][0] * rl;
    o.y = accO[dt][1] * rl;
    o.z = accO[dt][2] * rl;
    o.w = accO[dt][3] * rl;
    *(float4*)&out[((size_t)(b * 1024 + q0 + ln15)) * 1024 + h * 64 +
                   dt * 16 + lg * 4] = o;
  }
}

// ---------------------------------------------------------------------------
extern "C" void kernel_launch(void* const* d_in, const int* in_sizes, int n_in,
                              void* d_out, int out_size, void* d_ws,
                              size_t ws_size, hipStream_t stream) {
  const float* hs   = (const float*)d_in[0];
  const float* mask = (const float*)d_in[1];
  const float* rel1 = (const float*)d_in[2];
  const float* rel2 = (const float*)d_in[3];
  const float* Wq   = (const float*)d_in[4];
  const float* bq   = (const float*)d_in[5];
  const float* Wk   = (const float*)d_in[6];
  const float* bk   = (const float*)d_in[7];
  const float* Wv   = (const float*)d_in[8];
  const float* bv   = (const float*)d_in[9];

  char* ws = (char*)d_ws;
  __hip_bfloat16* hbf = (__hip_bfloat16*)(ws);              // 8 MB
  __hip_bfloat16* wbf = (__hip_bfloat16*)(ws + 8388608);    // 6 MB
  __hip_bfloat16* qb  = (__hip_bfloat16*)(ws + 14680064);   // 8 MB
  __hip_bfloat16* kfb = (__hip_bfloat16*)(ws + 23068672);   // 8 MB (K frag)
  __hip_bfloat16* vfb = (__hip_bfloat16*)(ws + 31457280);   // 8 MB (V^T frag)

  cvt_kernel<<<7168, 256, 0, stream>>>(hs, Wq, Wk, Wv, hbf, wbf);
  qkv_gemm<<<768, 256, 0, stream>>>(hbf, wbf, bq, bk, bv, qb, kfb, vfb);
  attn_kernel<<<1024, 256, 0, stream>>>(qb, kfb, vfb, rel1, rel2, mask,
                                        (float*)d_out);
}

// Round 8
// 171.589 us; speedup vs baseline: 1.9522x; 1.1695x over previous
//
#include <hip/hip_runtime.h>
#include <hip/hip_bf16.h>

typedef __attribute__((ext_vector_type(8))) short bf16x8;
typedef __attribute__((ext_vector_type(4))) float f32x4;

#define LDSG(g, l) __builtin_amdgcn_global_load_lds(                      \
    (const __attribute__((address_space(1))) void*)(g),                   \
    (__attribute__((address_space(3))) void*)(l), 16, 0, 0)

#define LOG2E 1.44269504088896f
#define RELSC 0.180336880111112f   /* 0.125 * log2(e) */

// ---------------- kernel 1: fp32 -> bf16 convert (hidden + Wq|Wk|Wv) --------
__global__ __launch_bounds__(256) void cvt_kernel(
    const float* __restrict__ hs,
    const float* __restrict__ wq, const float* __restrict__ wk,
    const float* __restrict__ wv,
    __hip_bfloat16* __restrict__ hbf, __hip_bfloat16* __restrict__ wbf)
{
  const int NH = (4 * 1024 * 1024) / 4;   // hidden quads
  const int NW = (1024 * 1024) / 4;       // per-W quads
  int i = blockIdx.x * 256 + threadIdx.x; // exact grid: NH + 3*NW quads
  float4 v;
  __hip_bfloat16* dst;
  if (i < NH) {
    v = ((const float4*)hs)[i];
    dst = hbf + (size_t)i * 4;
  } else {
    int j = i - NH;
    int which = j / NW, r = j - which * NW;
    const float* src = which == 0 ? wq : (which == 1 ? wk : wv);
    v = ((const float4*)src)[r];
    dst = wbf + (size_t)j * 4;
  }
  union { ushort4 u; __hip_bfloat16 b[4]; } o;
  o.b[0] = __float2bfloat16(v.x);
  o.b[1] = __float2bfloat16(v.y);
  o.b[2] = __float2bfloat16(v.z);
  o.b[3] = __float2bfloat16(v.w);
  *((ushort4*)dst) = o.u;
}

// ---------------- kernel 2: QKV GEMM  C[4096][3072] = A[4096][1024] @ W^T ---
// q scaled by 0.125*log2e, stored [b,h,s,d].
// k/v written PRE-FRAGMENTED in MFMA A-operand order per (bh, ktile):
//   K  chunk (ks*4+ct)*64+lane holds K[k=ct*16+(lane&15)][d=ks*32+(lane>>4)*8+e]
//   V^T chunk (ks*4+dt)*64+lane holds V[k=ks*32+(lane>>4)*8+e][d=dt*16+(lane&15)]
// so attention loads are fully contiguous 1KB instructions.
__global__ __launch_bounds__(256) void qkv_gemm(
    const __hip_bfloat16* __restrict__ A,  // [4096][1024]
    const __hip_bfloat16* __restrict__ W,  // [3072][1024] (q,k,v stacked)
    const float* __restrict__ bq, const float* __restrict__ bk,
    const float* __restrict__ bv,
    __hip_bfloat16* __restrict__ qo, __hip_bfloat16* __restrict__ ko,
    __hip_bfloat16* __restrict__ vo)
{
  const int K = 1024;
  __shared__ __hip_bfloat16 As[128 * 64];
  __shared__ __hip_bfloat16 Bs[128 * 64];
  const int bid = blockIdx.x;
  const int bm = bid & 31, bn = bid >> 5;
  const int m0 = bm * 128, n0 = bn * 128;
  const int tid = threadIdx.x, wid = tid >> 6, lane = tid & 63;
  const int wm = wid >> 1, wn = wid & 1;

  f32x4 acc[4][4] = {};

  const int srow = lane >> 3;              // 0..7 (row within 8-row group)
  const int schunk = (lane & 7) ^ srow;    // swizzled 16B-chunk in row

  for (int k0 = 0; k0 < K; k0 += 64) {
#pragma unroll
    for (int p = 0; p < 4; ++p) {
      int r = (wid * 4 + p) * 8 + srow;    // 0..127
      LDSG(&A[(size_t)(m0 + r) * K + k0 + schunk * 8], &As[(wid * 4 + p) * 512]);
      LDSG(&W[(size_t)(n0 + r) * K + k0 + schunk * 8], &Bs[(wid * 4 + p) * 512]);
    }
    __syncthreads();
#pragma unroll
    for (int ks = 0; ks < 2; ++ks) {
      bf16x8 af[4], bfr[4];
#pragma unroll
      for (int mi = 0; mi < 4; ++mi) {
        int row = wm * 64 + mi * 16 + (lane & 15);
        int slot = (ks * 4 + (lane >> 4)) ^ (lane & 7);
        af[mi] = *(const bf16x8*)((const char*)As + row * 128 + slot * 16);
      }
#pragma unroll
      for (int ni = 0; ni < 4; ++ni) {
        int row = wn * 64 + ni * 16 + (lane & 15);
        int slot = (ks * 4 + (lane >> 4)) ^ (lane & 7);
        bfr[ni] = *(const bf16x8*)((const char*)Bs + row * 128 + slot * 16);
      }
#pragma unroll
      for (int mi = 0; mi < 4; ++mi)
#pragma unroll
        for (int ni = 0; ni < 4; ++ni)
          acc[mi][ni] = __builtin_amdgcn_mfma_f32_16x16x32_bf16(
              af[mi], bfr[ni], acc[mi][ni], 0, 0, 0);
    }
    __syncthreads();
  }

  // epilogue. C/D layout: col = lane&15, row = (lane>>4)*4+j.
#pragma unroll
  for (int ni = 0; ni < 4; ++ni) {
    int n = n0 + wn * 64 + ni * 16 + (lane & 15);
    int which = n >> 10;         // 0=q 1=k 2=v (uniform per block)
    int h = (n >> 6) & 15;
    int d = n & 63;
    const float* bias = which == 0 ? bq : (which == 1 ? bk : bv);
    float bval = bias[n & 1023];
    if (which == 0) {
      // q: [b,h,s,d], pre-scaled by 0.125*log2e
#pragma unroll
      for (int mi = 0; mi < 4; ++mi) {
#pragma unroll
        for (int j = 0; j < 4; ++j) {
          int m = m0 + wm * 64 + mi * 16 + (lane >> 4) * 4 + j;
          int b = m >> 10, s = m & 1023;
          float val = (acc[mi][ni][j] + bval) * RELSC;
          qo[(((size_t)(b * 16 + h) << 10) + s) * 64 + d] = __float2bfloat16(val);
        }
      }
    } else if (which == 1) {
      // K fragment store (scalar scatter)
      int dks = d >> 5, dlg = (d >> 3) & 3, de = d & 7;
#pragma unroll
      for (int mi = 0; mi < 4; ++mi) {
#pragma unroll
        for (int j = 0; j < 4; ++j) {
          int m = m0 + wm * 64 + mi * 16 + (lane >> 4) * 4 + j;
          int b = m >> 10, s = m & 1023;
          size_t idx = ((((size_t)(b * 16 + h)) * 16 + (s >> 6)) * 512 +
                        (size_t)((dks * 4 + ((s >> 4) & 3)) * 64 + (s & 15) +
                                 16 * dlg)) * 8 + de;
          ko[idx] = __float2bfloat16(acc[mi][ni][j] + bval);
        }
      }
    } else {
      // V^T fragment store (ushort4: 4 consecutive k -> consecutive e)
      int dt = d >> 4, dl15 = d & 15;
#pragma unroll
      for (int mi = 0; mi < 4; ++mi) {
        int m = m0 + wm * 64 + mi * 16 + (lane >> 4) * 4;  // k0 (mod 4 == 0)
        int b = m >> 10, k = m & 1023;
        int kt = k >> 6, kks = (k >> 5) & 1, klg = (k >> 3) & 3, ke = k & 7;
        union { ushort4 u; __hip_bfloat16 bb[4]; } o;
#pragma unroll
        for (int j = 0; j < 4; ++j)
          o.bb[j] = __float2bfloat16(acc[mi][ni][j] + bval);
        size_t idx = ((((size_t)(b * 16 + h)) * 16 + kt) * 512 +
                      (size_t)((kks * 4 + dt) * 64 + dl15 + 16 * klg)) * 8 + ke;
        *(ushort4*)&vo[idx] = o.u;
      }
    }
  }
}

// ---------------- kernel 3: producer/consumer flash attention ---------------
// 512 threads = 8 waves. Waves 0-3 COMPUTE (16 q-rows each, r7 math:
// pre-fragmented K/V, fixed-max softmax). Waves 4-7 are pure STREAMERS:
// wave 4+w stages rel1/rel2 tiles for compute wave w, one tile ahead, into
// the 2-deep Rbuf via global_load_lds, then hits the barrier. The compiler's
// vmcnt(0)-drain-before-s_barrier is the producer handshake. Streamers have
// no dependent chain -> ~64KB/CU permanently outstanding -> HBM-rate-limited
// barrier rhythm (~2.6us/body) that fully hides consumer compute (~0.5us).
__global__ __launch_bounds__(512, 4) void attn_kernel(
    const __hip_bfloat16* __restrict__ qg, const __hip_bfloat16* __restrict__ kf,
    const __hip_bfloat16* __restrict__ vf,
    const float* __restrict__ rel1, const float* __restrict__ rel2,
    const float* __restrict__ mask, float* __restrict__ out)
{
  __shared__ float Rbuf[4][2][2][16][64];   // [cw][buf][rel][row][k] 64 KB
  __shared__ float Ml[1024];                // mask*log2e - 32, 4 KB
  __shared__ __hip_bfloat16 Ps[4][16 * 64]; // P transpose bounce, 8 KB

  const int bid = blockIdx.x;
  const int bh = bid & 63, qt = bid >> 6;   // bid%8==bh%8 -> bh pinned to XCD
  const int b = bh >> 4, h = bh & 15;
  const int tid = threadIdx.x, wid = tid >> 6, lane = tid & 63;
  const int lg = lane >> 4, ln15 = lane & 15;

  const size_t qbase = (size_t)bh << 16;    // bh * 1024 * 64
  const size_t fbase = (size_t)bh << 16;    // frag elems per bh

  // stage mask: Ml = mask*log2e - 32 (fixed softmax max), 512 thr x float2
  {
    float2 mv = *(const float2*)&mask[((size_t)b << 10) + tid * 2];
    float2 sm;
    sm.x = mv.x * LOG2E - 32.0f;
    sm.y = mv.y * LOG2E - 32.0f;
    *(float2*)&Ml[tid * 2] = sm;
  }

  if (wid >= 4) {
    // ------------------------- streamer wave ------------------------------
    const int cw = wid - 4;
    const int q0c = qt * 64 + cw * 16;
    const int r4 = lane >> 4, c15 = lane & 15;
    const float* relw1 = rel1 + ((size_t)bh << 20);
    const float* relw2 = rel2 + ((size_t)bh << 20);

    // prologue: tile 0 -> buf 0
#pragma unroll
    for (int p = 0; p < 4; ++p) {
      int rg = 4 * p + r4;
      int cg = c15 ^ (rg & 7);
      LDSG(&relw1[(size_t)(q0c + rg) * 1024 + cg * 4], &Rbuf[cw][0][0][4 * p][0]);
      LDSG(&relw2[(size_t)(q0c + rg) * 1024 + cg * 4], &Rbuf[cw][0][1][4 * p][0]);
    }
    __syncthreads();                        // barrier 0: mask + tile0 ready

    for (int t = 0; t < 15; ++t) {
      int buf = (t + 1) & 1;
      int kb = (t + 1) * 64;
#pragma unroll
      for (int p = 0; p < 4; ++p) {
        int rg = 4 * p + r4;
        int cg = c15 ^ (rg & 7);
        LDSG(&relw1[(size_t)(q0c + rg) * 1024 + kb + cg * 4],
             &Rbuf[cw][buf][0][4 * p][0]);
        LDSG(&relw2[(size_t)(q0c + rg) * 1024 + kb + cg * 4],
             &Rbuf[cw][buf][1][4 * p][0]);
      }
      __syncthreads();                      // barrier t+1 (vmcnt auto-drained)
    }
    return;                                 // consumers finish body 15 alone
  }

  // -------------------------- consumer wave -------------------------------
  const int q0 = qt * 64 + wid * 16;

  // Q as B-operand fragment: col=ln15=q, contraction d = ks*32 + lg*8 + jj
  bf16x8 qf[2];
  qf[0] = *(const bf16x8*)&qg[qbase + (size_t)(q0 + ln15) * 64 + lg * 8];
  qf[1] = *(const bf16x8*)&qg[qbase + (size_t)(q0 + ln15) * 64 + 32 + lg * 8];

  f32x4 accO[4] = {};
  float lrun = 0.f;

  __syncthreads();                          // barrier 0

  for (int t = 0; t < 16; ++t) {
    // pre-fragmented K/V: 8+8 contiguous 1KB loads (L2-resident)
    bf16x8 kfr[8], vfr[8];
#pragma unroll
    for (int i = 0; i < 8; ++i)
      kfr[i] = *(const bf16x8*)&kf[fbase + (size_t)t * 4096 + i * 512 + lane * 8];
#pragma unroll
    for (int i = 0; i < 8; ++i)
      vfr[i] = *(const bf16x8*)&vf[fbase + (size_t)t * 4096 + i * 512 + lane * 8];

    f32x4 st[4] = {};
#pragma unroll
    for (int ks = 0; ks < 2; ++ks)
#pragma unroll
      for (int ct = 0; ct < 4; ++ct)
        st[ct] = __builtin_amdgcn_mfma_f32_16x16x32_bf16(
            kfr[ks * 4 + ct], qf[ks], st[ct], 0, 0, 0);

    const char* Rb1 = (const char*)&Rbuf[wid][t & 1][0][0][0];
    const char* Rb2 = (const char*)&Rbuf[wid][t & 1][1][0][0];
    float p_[4][4];
#pragma unroll
    for (int ct = 0; ct < 4; ++ct) {
      int cc = ((ct * 4 + lg) ^ (ln15 & 7)) * 16;
      float4 rv1 = *(const float4*)(Rb1 + ln15 * 256 + cc);
      float4 rv2 = *(const float4*)(Rb2 + ln15 * 256 + cc);
      float4 mv = *(const float4*)&Ml[t * 64 + ct * 16 + lg * 4];
#pragma unroll
      for (int j = 0; j < 4; ++j) {
        float sv = st[ct][j] +
                   RELSC * (((const float*)&rv1)[j] + ((const float*)&rv2)[j]) +
                   ((const float*)&mv)[j];
        float e = __builtin_amdgcn_exp2f(sv);
        p_[ct][j] = e;
        lrun += e;
      }
    }

    // P -> bf16 via LDS bounce (wave-private, XOR-swizzled)
    __hip_bfloat16* Pw = &Ps[wid][0];
#pragma unroll
    for (int ct = 0; ct < 4; ++ct) {
      union { ushort4 u; __hip_bfloat16 bb[4]; } w;
#pragma unroll
      for (int j = 0; j < 4; ++j) w.bb[j] = __float2bfloat16(p_[ct][j]);
      *(ushort4*)((char*)Pw + ln15 * 128 +
                  ((ct * 32 + lg * 8) ^ ((ln15 & 7) << 4))) = w.u;
    }
    bf16x8 pt[2];
    pt[0] = *(const bf16x8*)((const char*)Pw + ln15 * 128 +
                             ((lg * 16) ^ ((ln15 & 7) << 4)));
    pt[1] = *(const bf16x8*)((const char*)Pw + ln15 * 128 +
                             ((64 + lg * 16) ^ ((ln15 & 7) << 4)));

#pragma unroll
    for (int ks = 0; ks < 2; ++ks)
#pragma unroll
      for (int dt = 0; dt < 4; ++dt)
        accO[dt] = __builtin_amdgcn_mfma_f32_16x16x32_bf16(
            vfr[ks * 4 + dt], pt[ks], accO[dt], 0, 0, 0);

    if (t < 15) __syncthreads();            // barriers 1..15 (match streamer)
  }

  // single final denominator reduce (q = ln15 column preserved)
  lrun += __shfl_xor(lrun, 16, 64);
  lrun += __shfl_xor(lrun, 32, 64);
  float rl = 1.0f / lrun;

  // epilogue: lane holds ctx^T[d=dt*16+lg*4+j][q=q0+ln15]; out fp32 [b,s,C]
#pragma unroll
  for (int dt = 0; dt < 4; ++dt) {
    float4 o;
    o.x = accO[dt][0] * rl;
    o.y = accO[dt][1] * rl;
    o.z = accO[dt][2] * rl;
    o.w = accO[dt][3] * rl;
    *(float4*)&out[((size_t)(b * 1024 + q0 + ln15)) * 1024 + h * 64 +
                   dt * 16 + lg * 4] = o;
  }
}

// ---------------------------------------------------------------------------
extern "C" void kernel_launch(void* const* d_in, const int* in_sizes, int n_in,
                              void* d_out, int out_size, void* d_ws,
                              size_t ws_size, hipStream_t stream) {
  const float* hs   = (const float*)d_in[0];
  const float* mask = (const float*)d_in[1];
  const float* rel1 = (const float*)d_in[2];
  const float* rel2 = (const float*)d_in[3];
  const float* Wq   = (const float*)d_in[4];
  const float* bq   = (const float*)d_in[5];
  const float* Wk   = (const float*)d_in[6];
  const float* bk   = (const float*)d_in[7];
  const float* Wv   = (const float*)d_in[8];
  const float* bv   = (const float*)d_in[9];

  char* ws = (char*)d_ws;
  __hip_bfloat16* hbf = (__hip_bfloat16*)(ws);              // 8 MB
  __hip_bfloat16* wbf = (__hip_bfloat16*)(ws + 8388608);    // 6 MB
  __hip_bfloat16* qb  = (__hip_bfloat16*)(ws + 14680064);   // 8 MB
  __hip_bfloat16* kfb = (__hip_bfloat16*)(ws + 23068672);   // 8 MB (K frag)
  __hip_bfloat16* vfb = (__hip_bfloat16*)(ws + 31457280);   // 8 MB (V^T frag)

  cvt_kernel<<<7168, 256, 0, stream>>>(hs, Wq, Wk, Wv, hbf, wbf);
  qkv_gemm<<<768, 256, 0, stream>>>(hbf, wbf, bq, bk, bv, qb, kfb, vfb);
  attn_kernel<<<1024, 512, 0, stream>>>(qb, kfb, vfb, rel1, rel2, mask,
                                        (float*)d_out);
}